// Round 15
// baseline (2098.267 us; speedup 1.0000x reference)
//
#include <hip/hip_runtime.h>
#include <hip/hip_bf16.h>

#define LAYERS 8
#define H_ 16
#define E_ 1024
#define D_ 64
#define FF_ 4096
#define V_ 2048
#define B_ 4
#define T_ 1024
#define MTOK (B_*T_)

typedef __bf16 bf16x8_t __attribute__((ext_vector_type(8)));
typedef __bf16 bf16x4_t __attribute__((ext_vector_type(4)));
typedef float f32x4_t __attribute__((ext_vector_type(4)));
typedef __hip_bfloat16 bf16_t;

__device__ __forceinline__ bf16_t f2b(float f) { return __float2bfloat16(f); }

// ---------------- embedding ----------------
__global__ void embed_kernel(const int* __restrict__ tokens,
                             const float* __restrict__ te,
                             const float* __restrict__ pe,
                             bf16_t* __restrict__ x) {
  int row = blockIdx.x;
  int tok = tokens[row];
  int t = threadIdx.x;
  float4 va = ((const float4*)(te + (size_t)tok * E_))[t];
  float4 vp = ((const float4*)(pe + (size_t)tok * E_))[t];
  bf16x4_t o;
  o[0] = (__bf16)(va.x + vp.x); o[1] = (__bf16)(va.y + vp.y);
  o[2] = (__bf16)(va.z + vp.z); o[3] = (__bf16)(va.w + vp.w);
  ((bf16x4_t*)(x + (size_t)row * E_))[t] = o;
}

// ---------------- layernorm ----------------
__global__ __launch_bounds__(256) void ln_kernel(const bf16_t* __restrict__ xin,
                                                 bf16_t* __restrict__ xout,
                                                 const float* __restrict__ g,
                                                 const float* __restrict__ b) {
  int row = blockIdx.x, tid = threadIdx.x;
  bf16x4_t v4 = ((const bf16x4_t*)(xin + (size_t)row * E_))[tid];
  float v0 = (float)v4[0], v1 = (float)v4[1], v2 = (float)v4[2], v3 = (float)v4[3];
  float s  = v0 + v1 + v2 + v3;
  float sq = v0*v0 + v1*v1 + v2*v2 + v3*v3;
  for (int off = 32; off; off >>= 1) {
    s  += __shfl_xor(s, off, 64);
    sq += __shfl_xor(sq, off, 64);
  }
  __shared__ float2 wred[4];
  if ((tid & 63) == 0) wred[tid >> 6] = make_float2(s, sq);
  __syncthreads();
  float2 w0 = wred[0], w1 = wred[1], w2 = wred[2], w3 = wred[3];
  float S = w0.x + w1.x + w2.x + w3.x, SQ = w0.y + w1.y + w2.y + w3.y;
  float mean = S * (1.0f / E_);
  float var  = SQ * (1.0f / E_) - mean * mean;
  float inv = rsqrtf(var + 1e-5f);
  float4 gv = ((const float4*)g)[tid];
  float4 bv = ((const float4*)b)[tid];
  bf16x4_t o;
  o[0] = (__bf16)((v0 - mean) * inv * gv.x + bv.x);
  o[1] = (__bf16)((v1 - mean) * inv * gv.y + bv.y);
  o[2] = (__bf16)((v2 - mean) * inv * gv.z + bv.z);
  o[3] = (__bf16)((v3 - mean) * inv * gv.w + bv.w);
  ((bf16x4_t*)(xout + (size_t)row * E_))[tid] = o;
}

// ---------------- fused split-K reduce + LayerNorm ----------------
__global__ __launch_bounds__(256) void reduce_ln_kernel(
    const bf16_t* __restrict__ p,
    const bf16_t* __restrict__ tin,
    const float* __restrict__ bias,
    bf16_t* __restrict__ r,
    bf16_t* __restrict__ tout,
    const float* __restrict__ g,
    const float* __restrict__ b) {
  int row = blockIdx.x, tid = threadIdx.x;
  size_t base = (size_t)row * E_ + tid * 4;
  bf16x4_t tv = *(const bf16x4_t*)(tin + base);
  bf16x4_t p0 = *(const bf16x4_t*)(p + base);
  bf16x4_t p1 = *(const bf16x4_t*)(p + (size_t)MTOK * E_ + base);
  float4 bv = ((const float4*)bias)[tid];
  float y0 = (float)tv[0] + (float)p0[0] + (float)p1[0] + bv.x;
  float y1 = (float)tv[1] + (float)p0[1] + (float)p1[1] + bv.y;
  float y2 = (float)tv[2] + (float)p0[2] + (float)p1[2] + bv.z;
  float y3 = (float)tv[3] + (float)p0[3] + (float)p1[3] + bv.w;
  bf16x4_t rv;
  rv[0] = (__bf16)y0; rv[1] = (__bf16)y1; rv[2] = (__bf16)y2; rv[3] = (__bf16)y3;
  *(bf16x4_t*)(r + base) = rv;
  float z0 = (float)rv[0], z1 = (float)rv[1], z2 = (float)rv[2], z3 = (float)rv[3];
  float s = z0 + z1 + z2 + z3, sq = z0*z0 + z1*z1 + z2*z2 + z3*z3;
  for (int off = 32; off; off >>= 1) {
    s  += __shfl_xor(s, off, 64);
    sq += __shfl_xor(sq, off, 64);
  }
  __shared__ float2 wred[4];
  if ((tid & 63) == 0) wred[tid >> 6] = make_float2(s, sq);
  __syncthreads();
  float2 w0 = wred[0], w1 = wred[1], w2 = wred[2], w3 = wred[3];
  float S = w0.x + w1.x + w2.x + w3.x, SQ = w0.y + w1.y + w2.y + w3.y;
  float mean = S * (1.0f / E_);
  float var  = SQ * (1.0f / E_) - mean * mean;
  float inv = rsqrtf(var + 1e-5f);
  float4 gv = ((const float4*)g)[tid];
  float4 b2v = ((const float4*)b)[tid];
  bf16x4_t o;
  o[0] = (__bf16)((z0 - mean) * inv * gv.x + b2v.x);
  o[1] = (__bf16)((z1 - mean) * inv * gv.y + b2v.y);
  o[2] = (__bf16)((z2 - mean) * inv * gv.z + b2v.z);
  o[3] = (__bf16)((z3 - mean) * inv * gv.w + b2v.w);
  *(bf16x4_t*)(tout + base) = o;
}

// ---------------- fused per-layer weight transpose: 6 ops, one dispatch ----------------
__global__ void prep_weights_kernel(const float* __restrict__ Wq,
                                    const float* __restrict__ Wk,
                                    const float* __restrict__ Wv,
                                    const float* __restrict__ Wo,
                                    const float* __restrict__ W1,
                                    const float* __restrict__ W2,
                                    bf16_t* __restrict__ WqkvT,
                                    bf16_t* __restrict__ WoT,
                                    bf16_t* __restrict__ W1T,
                                    bf16_t* __restrict__ W2T,
                                    int l) {
  __shared__ float tile[32][33];
  int bid = blockIdx.x;
  const float* src; bf16_t* dst; int R, C, r0, c0;
  if (bid < 3072) {
    int op = bid >> 10, rem = bid & 1023;
    int h = rem >> 6, tt = rem & 63;
    const float* W = (op == 0) ? Wq : (op == 1) ? Wk : Wv;
    src = W + (size_t)l * H_ * E_ * D_ + (size_t)h * E_ * D_;
    dst = WqkvT + (size_t)op * E_ * H_ * D_ + (size_t)h * E_ * D_;
    R = E_; C = D_; r0 = (tt >> 1) * 32; c0 = (tt & 1) * 32;
  } else if (bid < 4096) {
    int tt = bid - 3072;
    src = Wo + (size_t)l * H_ * D_ * E_; dst = WoT;
    R = H_ * D_; C = E_; r0 = (tt >> 5) * 32; c0 = (tt & 31) * 32;
  } else if (bid < 8192) {
    int tt = bid - 4096;
    src = W1 + (size_t)l * E_ * FF_; dst = W1T;
    R = E_; C = FF_; r0 = (tt >> 7) * 32; c0 = (tt & 127) * 32;
  } else {
    int tt = bid - 8192;
    src = W2 + (size_t)l * FF_ * E_; dst = W2T;
    R = FF_; C = E_; r0 = (tt >> 5) * 32; c0 = (tt & 31) * 32;
  }
  int tx = threadIdx.x, ty = threadIdx.y;
  for (int i = 0; i < 4; i++)
    tile[ty + i * 8][tx] = src[(size_t)(r0 + ty + i * 8) * C + (c0 + tx)];
  __syncthreads();
  for (int i = 0; i < 4; i++)
    dst[(size_t)(c0 + ty + i * 8) * R + (r0 + tx)] = f2b(tile[tx][ty + i * 8]);
}

// ---------------- single transpose (LM head) ----------------
__global__ void transpose_kernel(const float* __restrict__ in, bf16_t* __restrict__ out,
                                 int R, int C) {
  __shared__ float tile[32][33];
  int r0 = blockIdx.y * 32, c0 = blockIdx.x * 32;
  int tx = threadIdx.x, ty = threadIdx.y;
  for (int i = 0; i < 4; i++)
    tile[ty + i * 8][tx] = in[(size_t)(r0 + ty + i * 8) * C + (c0 + tx)];
  __syncthreads();
  for (int i = 0; i < 4; i++)
    out[(size_t)(c0 + ty + i * 8) * R + (r0 + tx)] = f2b(tile[tx][ty + i * 8]);
}

enum { MODE_F32 = 0, MODE_BF16 = 1, MODE_QKV = 2, MODE_BF16R = 3 };

__device__ __forceinline__ void gload16(const bf16_t* g, bf16_t* l) {
  __builtin_amdgcn_global_load_lds((const __attribute__((address_space(1))) void*)g,
                                   (__attribute__((address_space(3))) void*)l, 16, 0, 0);
}

// bijective XCD-aware swizzle (m204)
__device__ __forceinline__ int xcd_swz(int flat, int nwg) {
  int q = nwg >> 3, r = nwg & 7;
  int xcd = flat & 7, idx = flat >> 3;
  return (xcd < r ? xcd * (q + 1) : r * (q + 1) + (xcd - r) * q) + idx;
}

// ---------------- gemm97: 128x128, BK=32, 4 waves, dbuf+prefetch ----------
#define BK 32
template <int BM, int BN, int MODE>
__global__ __launch_bounds__(256) void gemm97_kernel(
    const bf16_t* __restrict__ A, long long sAz, int lda,
    const bf16_t* __restrict__ Bt, long long sBz, int ldb,
    void* __restrict__ C, long long sCz,
    const float* __restrict__ bias,
    const void* __restrict__ resid,
    int M, int N, int K, int relu) {
  constexpr int FR = BM / 32, FC = BN / 32;
  constexpr int A_ISS = BM / 64, B_ISS = BN / 64;
  __shared__ __align__(16) bf16_t As[2][BM * BK];
  __shared__ __align__(16) bf16_t Bs[2][BN * BK];
  int tid = threadIdx.x;
  int z = blockIdx.z;
  int nwg = gridDim.x * gridDim.y;
  int flat = xcd_swz(blockIdx.y * gridDim.x + blockIdx.x, nwg);
  int m0 = (flat / gridDim.x) * BM, n0 = (flat % gridDim.x) * BN;
  const bf16_t* Ab = A + (size_t)z * sAz + (size_t)m0 * lda;
  const bf16_t* Bb = Bt + (size_t)z * sBz + (size_t)n0 * ldb;
  int lane = tid & 63, wave = tid >> 6;
  int wr = (wave >> 1) * (BM / 2), wc = (wave & 1) * (BN / 2);
  int lr = lane & 15, lk = (lane >> 4) * 8;
  int srow = tid >> 2;
  int scol = (tid & 3) * 8;

  f32x4_t acc[FR][FC];
  for (int i = 0; i < FR; i++)
    for (int j = 0; j < FC; j++)
      acc[i][j] = (f32x4_t){0.f, 0.f, 0.f, 0.f};

  auto stage = [&](int buf, int k0) {
#pragma unroll
    for (int i = 0; i < A_ISS; i++)
      gload16(Ab + (size_t)(i * 64 + srow) * lda + k0 + scol, &As[buf][i * 2048 + wave * 512]);
#pragma unroll
    for (int i = 0; i < B_ISS; i++)
      gload16(Bb + (size_t)(i * 64 + srow) * ldb + k0 + scol, &Bs[buf][i * 2048 + wave * 512]);
  };

  int nk = K / BK;
  stage(0, 0);
  __syncthreads();
  int cur = 0;
  for (int kt = 0; kt < nk; ++kt) {
    if (kt + 1 < nk) stage(cur ^ 1, (kt + 1) * BK);
    bf16x8_t af[FR], bfv[FC];
#pragma unroll
    for (int i = 0; i < FR; i++)
      af[i] = *(const bf16x8_t*)(&As[cur][(wr + i * 16 + lr) * BK + lk]);
#pragma unroll
    for (int j = 0; j < FC; j++)
      bfv[j] = *(const bf16x8_t*)(&Bs[cur][(wc + j * 16 + lr) * BK + lk]);
#pragma unroll
    for (int i = 0; i < FR; i++)
#pragma unroll
      for (int j = 0; j < FC; j++)
        acc[i][j] = __builtin_amdgcn_mfma_f32_16x16x32_bf16(af[i], bfv[j], acc[i][j], 0, 0, 0);
    __syncthreads();
    cur ^= 1;
  }

#pragma unroll
  for (int i = 0; i < FR; i++)
#pragma unroll
    for (int j = 0; j < FC; j++) {
      f32x4_t v = acc[i][j];
      int n = n0 + wc + j * 16 + lr;
      int mb = m0 + wr + i * 16 + (lane >> 4) * 4;
#pragma unroll
      for (int r = 0; r < 4; r++) {
        int m = mb + r;
        float val = v[r];
        if (bias) val += bias[n];
        if (relu) val = fmaxf(val, 0.f);
        if (MODE == MODE_F32) {
          size_t idx = (size_t)z * sCz + (size_t)m * N + n;
          ((float*)C)[idx] = val;
        } else if (MODE == MODE_BF16) {
          size_t idx = (size_t)z * sCz + (size_t)m * N + n;
          ((bf16_t*)C)[idx] = f2b(val);
        } else if (MODE == MODE_BF16R) {
          size_t idx = (size_t)m * N + n;
          val += __bfloat162float(((const bf16_t*)resid)[idx]);
          ((bf16_t*)C)[idx] = f2b(val);
        } else { // MODE_QKV
          int sect = n >> 10, hd = n & 1023, h = hd >> 6, d = hd & 63;
          int b = m >> 10, t = m & 1023;
          size_t base = (size_t)sect * ((size_t)B_ * H_ * T_ * D_);
          size_t idx = base + ((size_t)(b * H_ + h) << 16) +
                       (sect == 2 ? (size_t)((d << 10) + t) : (size_t)((t << 6) + d));
          ((bf16_t*)C)[idx] = f2b(val);
        }
      }
    }
}

// ---------------- gemm3: 256x128, BK=64, 8 waves, triple-buffer + counted vmcnt ----------
template <int MODE>
__global__ __launch_bounds__(512) void gemm3_kernel(
    const bf16_t* __restrict__ A, int lda,
    const bf16_t* __restrict__ Bt, int ldb,
    void* __restrict__ C, long long sCz,
    const float* __restrict__ bias,
    int M, int N, int kspan, int relu) {
  constexpr int ABUFE = 256 * 64;
  constexpr int BBUFE = 128 * 64;
  __shared__ __align__(16) bf16_t LA[3 * ABUFE];
  __shared__ __align__(16) bf16_t LB[3 * BBUFE];
  int tid = threadIdx.x, lane = tid & 63, wave = tid >> 6;
  int wm = wave >> 1, wn = wave & 1;
  int z = blockIdx.z;
  int nwg = gridDim.x * gridDim.y;
  int flat = xcd_swz(blockIdx.y * gridDim.x + blockIdx.x, nwg);
  int m0 = (flat / gridDim.x) * 256, n0 = (flat % gridDim.x) * 128;
  const bf16_t* Ab = A + (size_t)m0 * lda + (size_t)z * kspan;
  const bf16_t* Bb = Bt + (size_t)n0 * ldb + (size_t)z * kspan;
  int sr = lane & 15, sc = (lane >> 4) * 8;

  f32x4_t acc[4][4];
#pragma unroll
  for (int i = 0; i < 4; i++)
#pragma unroll
    for (int j = 0; j < 4; j++)
      acc[i][j] = (f32x4_t){0.f, 0.f, 0.f, 0.f};

  auto stageh = [&](int b, int kt, int h) {
    int kg = kt * 64;
#pragma unroll
    for (int ch = 0; ch < 2; ch++) {
      int sub = wave * 4 + 2 * h + ch;
      gload16(Ab + (size_t)((sub >> 1) * 16 + sr) * lda + kg + (sub & 1) * 32 + sc,
              LA + b * ABUFE + sub * 512);
    }
    {
      int sub = wave * 2 + h;
      gload16(Bb + (size_t)((sub >> 1) * 16 + sr) * ldb + kg + (sub & 1) * 32 + sc,
              LB + b * BBUFE + sub * 512);
    }
  };

  auto phase = [&](int b, int ks, int t, int nk) {
    bf16x8_t af[4], bfv[4];
    unsigned abase = (unsigned)(size_t)(LA + b * ABUFE);
    unsigned bbase = (unsigned)(size_t)(LB + b * BBUFE);
#pragma unroll
    for (int i = 0; i < 4; i++) {
      unsigned ad = abase + (unsigned)((((wm * 4 + i) * 2 + ks) * 512 + lane * 8) * 2);
      asm volatile("ds_read_b128 %0, %1" : "=v"(af[i]) : "v"(ad));
    }
#pragma unroll
    for (int j = 0; j < 4; j++) {
      unsigned bd = bbase + (unsigned)((((wn * 4 + j) * 2 + ks) * 512 + lane * 8) * 2);
      asm volatile("ds_read_b128 %0, %1" : "=v"(bfv[j]) : "v"(bd));
    }
    if (t + 2 < nk) stageh((t + 2) % 3, t + 2, ks);
    __builtin_amdgcn_s_barrier();
    asm volatile("s_waitcnt lgkmcnt(0)" ::: "memory");
    __builtin_amdgcn_sched_barrier(0);
    __builtin_amdgcn_s_setprio(1);
#pragma unroll
    for (int i = 0; i < 4; i++)
#pragma unroll
      for (int j = 0; j < 4; j++)
        acc[i][j] = __builtin_amdgcn_mfma_f32_16x16x32_bf16(af[i], bfv[j], acc[i][j], 0, 0, 0);
    __builtin_amdgcn_s_setprio(0);
  };

  int nk = kspan / 64;
  stageh(0, 0, 0); stageh(0, 0, 1);
  stageh(1, 1, 0); stageh(1, 1, 1);
  for (int t = 0; t < nk; ++t) {
    int b = t % 3;
    if (t + 1 < nk) { asm volatile("s_waitcnt vmcnt(6)" ::: "memory"); }
    else            { asm volatile("s_waitcnt vmcnt(0)" ::: "memory"); }
    __builtin_amdgcn_s_barrier();
    phase(b, 0, t, nk);
    phase(b, 1, t, nk);
  }

#pragma unroll
  for (int i = 0; i < 4; i++)
#pragma unroll
    for (int j = 0; j < 4; j++) {
      f32x4_t v = acc[i][j];
      int n = n0 + wn * 64 + j * 16 + (lane & 15);
      int mb = m0 + wm * 64 + i * 16 + (lane >> 4) * 4;
#pragma unroll
      for (int r = 0; r < 4; r++) {
        int m = mb + r;
        float val = v[r];
        if (bias) val += bias[n];
        if (relu) val = fmaxf(val, 0.f);
        if (MODE == MODE_F32) {
          size_t idx = (size_t)z * sCz + (size_t)m * N + n;
          ((float*)C)[idx] = val;
        } else {
          size_t idx = (size_t)z * sCz + (size_t)m * N + n;
          ((bf16_t*)C)[idx] = f2b(val);
        }
      }
    }
}

// ---------------- flash attention: QBLK=64, 4 waves + defer-max (T13) ----------------
#define KPAD 72

__global__ __launch_bounds__(256) void flash_kernel(
    const bf16_t* __restrict__ q,
    const bf16_t* __restrict__ kk,
    const bf16_t* __restrict__ vt,
    bf16_t* __restrict__ o) {
  __shared__ __align__(16) bf16_t Ks[64 * KPAD];
  __shared__ __align__(16) bf16_t Vs[64 * KPAD];
  __shared__ __align__(16) bf16_t Ps[4][16 * KPAD];
  int bid = blockIdx.x;
  int qi = 15 - (bid >> 6);
  int bh = bid & 63;
  int b = bh >> 4, h = bh & 15;
  const bf16_t* qb = q + ((size_t)bh << 16);
  const bf16_t* kb = kk + ((size_t)bh << 16);
  const bf16_t* vb = vt + ((size_t)bh << 16);
  int tid = threadIdx.x, lane = tid & 63, wave = tid >> 6;
  int lr = lane & 15, lg = lane >> 4;
  int qbase = qi * 64;

  bf16x8_t qf[2];
  {
    const bf16_t* qrow = qb + (size_t)(qbase + wave * 16 + lr) * D_ + lg * 8;
    qf[0] = *(const bf16x8_t*)(qrow);
    qf[1] = *(const bf16x8_t*)(qrow + 32);
  }

  float m_r[4], l_r[4];
  f32x4_t oc[4];
#pragma unroll
  for (int r = 0; r < 4; r++) { m_r[r] = -1e30f; l_r[r] = 0.f; }
#pragma unroll
  for (int j = 0; j < 4; j++) oc[j] = (f32x4_t){0.f, 0.f, 0.f, 0.f};

  int srow = tid >> 2, scol = (tid & 3) * 16;

  bf16x8_t k0, k1, v0, v1;
  {
    const bf16_t* kg = kb + (size_t)srow * D_ + scol;
    k0 = *(const bf16x8_t*)kg;
    k1 = *(const bf16x8_t*)(kg + 8);
    const bf16_t* vg = vb + (size_t)srow * T_ + scol;
    v0 = *(const bf16x8_t*)vg;
    v1 = *(const bf16x8_t*)(vg + 8);
  }

  for (int s = 0; s <= qi; s++) {
    __syncthreads();
    *(bf16x8_t*)(&Ks[srow * KPAD + scol]) = k0;
    *(bf16x8_t*)(&Ks[srow * KPAD + scol + 8]) = k1;
    *(bf16x8_t*)(&Vs[srow * KPAD + scol]) = v0;
    *(bf16x8_t*)(&Vs[srow * KPAD + scol + 8]) = v1;
    __syncthreads();

    if (s < qi) {
      int kv1 = (s + 1) * 64;
      const bf16_t* kg = kb + (size_t)(kv1 + srow) * D_ + scol;
      k0 = *(const bf16x8_t*)kg;
      k1 = *(const bf16x8_t*)(kg + 8);
      const bf16_t* vg = vb + (size_t)srow * T_ + kv1 + scol;
      v0 = *(const bf16x8_t*)vg;
      v1 = *(const bf16x8_t*)(vg + 8);
    }

    int kv0 = s * 64;
    f32x4_t sc[4];
#pragma unroll
    for (int j = 0; j < 4; j++) {
      f32x4_t a = (f32x4_t){0.f, 0.f, 0.f, 0.f};
      bf16x8_t b0 = *(const bf16x8_t*)(&Ks[(j * 16 + lr) * KPAD + lg * 8]);
      bf16x8_t b1 = *(const bf16x8_t*)(&Ks[(j * 16 + lr) * KPAD + lg * 8 + 32]);
      a = __builtin_amdgcn_mfma_f32_16x16x32_bf16(qf[0], b0, a, 0, 0, 0);
      a = __builtin_amdgcn_mfma_f32_16x16x32_bf16(qf[1], b1, a, 0, 0, 0);
      sc[j] = a;
    }
    if (s == qi) {
#pragma unroll
      for (int j = 0; j < 4; j++)
#pragma unroll
        for (int r = 0; r < 4; r++) {
          int kvp = kv0 + j * 16 + lr;
          int qp  = qbase + wave * 16 + lg * 4 + r;
          sc[j][r] = (kvp <= qp) ? sc[j][r] * 0.125f : -1e30f;
        }
    } else {
#pragma unroll
      for (int j = 0; j < 4; j++)
#pragma unroll
        for (int r = 0; r < 4; r++) sc[j][r] *= 0.125f;
    }

    // tile row-max per row (wave-parallel 16-lane reduce)
    float pm[4];
#pragma unroll
    for (int r = 0; r < 4; r++) {
      float v = fmaxf(fmaxf(sc[0][r], sc[1][r]), fmaxf(sc[2][r], sc[3][r]));
      v = fmaxf(v, __shfl_xor(v, 1, 64));
      v = fmaxf(v, __shfl_xor(v, 2, 64));
      v = fmaxf(v, __shfl_xor(v, 4, 64));
      v = fmaxf(v, __shfl_xor(v, 8, 64));
      pm[r] = v;
    }
    // defer-max (T13): only rescale when some row's max grew by > 8
    bool ok = (pm[0] - m_r[0] <= 8.f) && (pm[1] - m_r[1] <= 8.f) &&
              (pm[2] - m_r[2] <= 8.f) && (pm[3] - m_r[3] <= 8.f);
    if (!__all(ok)) {
#pragma unroll
      for (int r = 0; r < 4; r++) {
        float mn = fmaxf(m_r[r], pm[r]);
        float ex = __expf(m_r[r] - mn);
        m_r[r] = mn;
        l_r[r] *= ex;
#pragma unroll
        for (int j = 0; j < 4; j++) oc[j][r] *= ex;
      }
    }
#pragma unroll
    for (int j = 0; j < 4; j++)
#pragma unroll
      for (int r = 0; r < 4; r++) {
        float p = __expf(sc[j][r] - m_r[r]);   // bounded by e^8 when deferred
        l_r[r] += p;
        Ps[wave][(lg * 4 + r) * KPAD + j * 16 + lr] = f2b(p);
      }

    bf16x8_t pa0 = *(const bf16x8_t*)(&Ps[wave][lr * KPAD + lg * 8]);
    bf16x8_t pa1 = *(const bf16x8_t*)(&Ps[wave][lr * KPAD + lg * 8 + 32]);
#pragma unroll
    for (int j = 0; j < 4; j++) {
      bf16x8_t vb0 = *(const bf16x8_t*)(&Vs[(j * 16 + lr) * KPAD + lg * 8]);
      bf16x8_t vb1 = *(const bf16x8_t*)(&Vs[(j * 16 + lr) * KPAD + lg * 8 + 32]);
      oc[j] = __builtin_amdgcn_mfma_f32_16x16x32_bf16(pa0, vb0, oc[j], 0, 0, 0);
      oc[j] = __builtin_amdgcn_mfma_f32_16x16x32_bf16(pa1, vb1, oc[j], 0, 0, 0);
    }
  }

#pragma unroll
  for (int r = 0; r < 4; r++) {
    float v = l_r[r];
    v += __shfl_xor(v, 1, 64);
    v += __shfl_xor(v, 2, 64);
    v += __shfl_xor(v, 4, 64);
    v += __shfl_xor(v, 8, 64);
    l_r[r] = 1.f / v;
  }
  bf16_t* ob = o + ((size_t)(b * T_ + qbase + wave * 16)) * (H_ * D_) + h * D_;
#pragma unroll
  for (int j = 0; j < 4; j++)
#pragma unroll
    for (int r = 0; r < 4; r++) {
      int qrow = lg * 4 + r;
      ob[(size_t)qrow * (H_ * D_) + j * 16 + lr] = f2b(oc[j][r] * l_r[r]);
    }
}

// ---------------- host launch ----------------
extern "C" void kernel_launch(void* const* d_in, const int* in_sizes, int n_in,
                              void* d_out, int out_size, void* d_ws, size_t ws_size,
                              hipStream_t stream) {
  (void)in_sizes; (void)n_in; (void)out_size; (void)ws_size;
  const int*   tokens = (const int*)d_in[0];
  const float* tok_emb = (const float*)d_in[1];
  const float* pos_emb = (const float*)d_in[2];
  const float* Wq = (const float*)d_in[3];
  const float* Wk = (const float*)d_in[4];
  const float* Wv = (const float*)d_in[5];
  const float* Wo = (const float*)d_in[6];
  const float* bo = (const float*)d_in[7];
  const float* ln1_g = (const float*)d_in[8];
  const float* ln1_b = (const float*)d_in[9];
  const float* ln2_g = (const float*)d_in[10];
  const float* ln2_b = (const float*)d_in[11];
  const float* W1 = (const float*)d_in[12];
  const float* b1 = (const float*)d_in[13];
  const float* W2 = (const float*)d_in[14];
  const float* b2 = (const float*)d_in[15];
  const float* lnf_g = (const float*)d_in[16];
  const float* lnf_b = (const float*)d_in[17];
  const float* Wlm = (const float*)d_in[18];
  const float* blm = (const float*)d_in[19];

  char* w = (char*)d_ws;
  size_t off = 0;
  auto alloc = [&](size_t bytes) { void* p = (void*)(w + off); off += (bytes + 255) & ~(size_t)255; return p; };
  bf16_t* r    = (bf16_t*)alloc((size_t)MTOK * E_ * 2);
  bf16_t* t    = (bf16_t*)alloc((size_t)MTOK * E_ * 2);
  bf16_t* q    = (bf16_t*)alloc((size_t)B_ * H_ * T_ * D_ * 2);
  bf16_t* kk   = (bf16_t*)alloc((size_t)B_ * H_ * T_ * D_ * 2);
  bf16_t* vt   = (bf16_t*)alloc((size_t)B_ * H_ * T_ * D_ * 2);
  bf16_t* o    = (bf16_t*)alloc((size_t)MTOK * E_ * 2);
  bf16_t* h1   = (bf16_t*)alloc((size_t)MTOK * FF_ * 2);
  bf16_t* WqkvT = (bf16_t*)alloc((size_t)3 * E_ * H_ * D_ * 2);
  bf16_t* WoT  = (bf16_t*)alloc((size_t)E_ * H_ * D_ * 2);
  bf16_t* W1T  = (bf16_t*)alloc((size_t)E_ * FF_ * 2);
  bf16_t* W2T  = (bf16_t*)alloc((size_t)E_ * FF_ * 2);
  bf16_t* WlmT = (bf16_t*)alloc((size_t)E_ * V_ * 2);
  bf16_t* p2   = (bf16_t*)alloc((size_t)2 * MTOK * E_ * 2);

  embed_kernel<<<MTOK, 256, 0, stream>>>(tokens, tok_emb, pos_emb, r);
  transpose_kernel<<<dim3(V_ / 32, E_ / 32), dim3(32, 8), 0, stream>>>(Wlm, WlmT, E_, V_);
  ln_kernel<<<MTOK, 256, 0, stream>>>(r, t, ln1_g, ln1_b);

  for (int l = 0; l < LAYERS; l++) {
    prep_weights_kernel<<<12288, dim3(32, 8), 0, stream>>>(
        Wq, Wk, Wv, Wo, W1, W2, WqkvT, WoT, W1T, W2T, l);

    gemm97_kernel<128, 128, MODE_QKV><<<dim3(24, 32, 1), 256, 0, stream>>>(
        t, 0, E_, WqkvT, 0, E_, q, 0, nullptr, nullptr, MTOK, 3 * H_ * D_, E_, 0);

    flash_kernel<<<1024, 256, 0, stream>>>(q, kk, vt, o);

    gemm97_kernel<128, 128, MODE_BF16R><<<dim3(8, 32, 1), 256, 0, stream>>>(
        o, 0, H_ * D_, WoT, 0, H_ * D_, r, 0, bo + l * E_, t, MTOK, E_, H_ * D_, 0);

    ln_kernel<<<MTOK, 256, 0, stream>>>(r, t, ln2_g + l * E_, ln2_b + l * E_);

    gemm3_kernel<MODE_BF16><<<dim3(32, 16, 1), 512, 0, stream>>>(
        t, E_, W1T, E_, h1, 0, b1 + l * FF_, MTOK, FF_, E_, 1);
    gemm3_kernel<MODE_BF16><<<dim3(8, 16, 2), 512, 0, stream>>>(
        h1, FF_, W2T, FF_, p2, (long long)MTOK * E_, nullptr, MTOK, E_, FF_ / 2, 0);
    const float* gn = (l + 1 < LAYERS) ? (ln1_g + (l + 1) * E_) : lnf_g;
    const float* bn = (l + 1 < LAYERS) ? (ln1_b + (l + 1) * E_) : lnf_b;
    reduce_ln_kernel<<<MTOK, 256, 0, stream>>>(p2, t, b2 + l * E_, r, t, gn, bn);
  }

  gemm3_kernel<MODE_F32><<<dim3(16, 16, 1), 512, 0, stream>>>(
      t, E_, WlmT, E_, d_out, 0, blm, MTOK, V_, E_, 0);
}

// Round 16
// 2076.206 us; speedup vs baseline: 1.0106x; 1.0106x over previous
//
#include <hip/hip_runtime.h>
#include <hip/hip_bf16.h>

#define LAYERS 8
#define H_ 16
#define E_ 1024
#define D_ 64
#define FF_ 4096
#define V_ 2048
#define B_ 4
#define T_ 1024
#define MTOK (B_*T_)

typedef __bf16 bf16x8_t __attribute__((ext_vector_type(8)));
typedef __bf16 bf16x4_t __attribute__((ext_vector_type(4)));
typedef float f32x4_t __attribute__((ext_vector_type(4)));
typedef __hip_bfloat16 bf16_t;

__device__ __forceinline__ bf16_t f2b(float f) { return __float2bfloat16(f); }

// ---------------- embedding ----------------
__global__ void embed_kernel(const int* __restrict__ tokens,
                             const float* __restrict__ te,
                             const float* __restrict__ pe,
                             bf16_t* __restrict__ x) {
  int row = blockIdx.x;
  int tok = tokens[row];
  int t = threadIdx.x;
  float4 va = ((const float4*)(te + (size_t)tok * E_))[t];
  float4 vp = ((const float4*)(pe + (size_t)tok * E_))[t];
  bf16x4_t o;
  o[0] = (__bf16)(va.x + vp.x); o[1] = (__bf16)(va.y + vp.y);
  o[2] = (__bf16)(va.z + vp.z); o[3] = (__bf16)(va.w + vp.w);
  ((bf16x4_t*)(x + (size_t)row * E_))[t] = o;
}

// ---------------- layernorm: 2 rows/block, 128 thr/row, bf16x8 (16B/lane) ----------------
__global__ __launch_bounds__(256) void ln_kernel(const bf16_t* __restrict__ xin,
                                                 bf16_t* __restrict__ xout,
                                                 const float* __restrict__ g,
                                                 const float* __restrict__ b) {
  int tid = threadIdx.x;
  int row = blockIdx.x * 2 + (tid >> 7);
  int li = tid & 127;
  size_t base = (size_t)row * E_ + li * 8;
  bf16x8_t v8 = *(const bf16x8_t*)(xin + base);
  float z[8];
  float s = 0.f, sq = 0.f;
#pragma unroll
  for (int j = 0; j < 8; j++) { z[j] = (float)v8[j]; s += z[j]; sq += z[j] * z[j]; }
  for (int off = 32; off; off >>= 1) {
    s  += __shfl_xor(s, off, 64);
    sq += __shfl_xor(sq, off, 64);
  }
  __shared__ float2 wred[4];
  if ((tid & 63) == 0) wred[tid >> 6] = make_float2(s, sq);
  __syncthreads();
  int wb = (tid >> 7) << 1;
  float S = wred[wb].x + wred[wb + 1].x, SQ = wred[wb].y + wred[wb + 1].y;
  float mean = S * (1.0f / E_);
  float var  = SQ * (1.0f / E_) - mean * mean;
  float inv = rsqrtf(var + 1e-5f);
  float4 g0 = *(const float4*)(g + li * 8), g1 = *(const float4*)(g + li * 8 + 4);
  float4 b0 = *(const float4*)(b + li * 8), b1 = *(const float4*)(b + li * 8 + 4);
  float gg[8] = {g0.x, g0.y, g0.z, g0.w, g1.x, g1.y, g1.z, g1.w};
  float bb[8] = {b0.x, b0.y, b0.z, b0.w, b1.x, b1.y, b1.z, b1.w};
  bf16x8_t o;
#pragma unroll
  for (int j = 0; j < 8; j++) o[j] = (__bf16)((z[j] - mean) * inv * gg[j] + bb[j]);
  *(bf16x8_t*)(xout + base) = o;
}

// ---------------- fused split-K reduce + LayerNorm: 2 rows/block, bf16x8 ----------------
__global__ __launch_bounds__(256) void reduce_ln_kernel(
    const bf16_t* __restrict__ p,
    const bf16_t* __restrict__ tin,
    const float* __restrict__ bias,
    bf16_t* __restrict__ r,
    bf16_t* __restrict__ tout,
    const float* __restrict__ g,
    const float* __restrict__ b) {
  int tid = threadIdx.x;
  int row = blockIdx.x * 2 + (tid >> 7);
  int li = tid & 127;
  size_t base = (size_t)row * E_ + li * 8;
  bf16x8_t tv = *(const bf16x8_t*)(tin + base);
  bf16x8_t p0 = *(const bf16x8_t*)(p + base);
  bf16x8_t p1 = *(const bf16x8_t*)(p + (size_t)MTOK * E_ + base);
  float4 c0 = *(const float4*)(bias + li * 8), c1 = *(const float4*)(bias + li * 8 + 4);
  float bb[8] = {c0.x, c0.y, c0.z, c0.w, c1.x, c1.y, c1.z, c1.w};
  bf16x8_t rv;
  float z[8];
  float s = 0.f, sq = 0.f;
#pragma unroll
  for (int j = 0; j < 8; j++) {
    float y = (float)tv[j] + (float)p0[j] + (float)p1[j] + bb[j];
    rv[j] = (__bf16)y;
    z[j] = (float)rv[j];          // stats over rounded bf16 (matches split-kernel semantics)
    s += z[j]; sq += z[j] * z[j];
  }
  *(bf16x8_t*)(r + base) = rv;
  for (int off = 32; off; off >>= 1) {
    s  += __shfl_xor(s, off, 64);
    sq += __shfl_xor(sq, off, 64);
  }
  __shared__ float2 wred[4];
  if ((tid & 63) == 0) wred[tid >> 6] = make_float2(s, sq);
  __syncthreads();
  int wb = (tid >> 7) << 1;
  float S = wred[wb].x + wred[wb + 1].x, SQ = wred[wb].y + wred[wb + 1].y;
  float mean = S * (1.0f / E_);
  float var  = SQ * (1.0f / E_) - mean * mean;
  float inv = rsqrtf(var + 1e-5f);
  float4 g0 = *(const float4*)(g + li * 8), g1 = *(const float4*)(g + li * 8 + 4);
  float4 d0 = *(const float4*)(b + li * 8), d1 = *(const float4*)(b + li * 8 + 4);
  float gg[8] = {g0.x, g0.y, g0.z, g0.w, g1.x, g1.y, g1.z, g1.w};
  float dd[8] = {d0.x, d0.y, d0.z, d0.w, d1.x, d1.y, d1.z, d1.w};
  bf16x8_t o;
#pragma unroll
  for (int j = 0; j < 8; j++) o[j] = (__bf16)((z[j] - mean) * inv * gg[j] + dd[j]);
  *(bf16x8_t*)(tout + base) = o;
}

// ---------------- fused per-layer weight transpose: 64x64 tiles, f32x4 read / bf16x8 write ----
// tiles: [0,768) qkv  [768,1024) Wo  [1024,2048) W1  [2048,3072) W2
__global__ __launch_bounds__(256) void prep_weights_kernel(
    const float* __restrict__ Wq, const float* __restrict__ Wk,
    const float* __restrict__ Wv, const float* __restrict__ Wo,
    const float* __restrict__ W1, const float* __restrict__ W2,
    bf16_t* __restrict__ WqkvT, bf16_t* __restrict__ WoT,
    bf16_t* __restrict__ W1T, bf16_t* __restrict__ W2T, int l) {
  __shared__ float tile[64][65];
  int bid = blockIdx.x, tid = threadIdx.x;
  const float* src; bf16_t* dst; int R, C, r0, c0;
  if (bid < 768) {
    int op = bid >> 8, rem = bid & 255;
    int h = rem >> 4, tt = rem & 15;
    const float* W = (op == 0) ? Wq : (op == 1) ? Wk : Wv;
    src = W + (size_t)l * H_ * E_ * D_ + (size_t)h * E_ * D_;
    dst = WqkvT + (size_t)op * E_ * H_ * D_ + (size_t)h * E_ * D_;
    R = E_; C = D_; r0 = tt * 64; c0 = 0;
  } else if (bid < 1024) {
    int tt = bid - 768;
    src = Wo + (size_t)l * H_ * D_ * E_; dst = WoT;
    R = H_ * D_; C = E_; r0 = (tt >> 4) * 64; c0 = (tt & 15) * 64;
  } else if (bid < 2048) {
    int tt = bid - 1024;
    src = W1 + (size_t)l * E_ * FF_; dst = W1T;
    R = E_; C = FF_; r0 = (tt >> 6) * 64; c0 = (tt & 63) * 64;
  } else {
    int tt = bid - 2048;
    src = W2 + (size_t)l * FF_ * E_; dst = W2T;
    R = FF_; C = E_; r0 = (tt >> 4) * 64; c0 = (tt & 15) * 64;
  }
#pragma unroll
  for (int i = 0; i < 4; i++) {
    int idx = i * 256 + tid;
    int row = idx >> 4, q4 = (idx & 15) * 4;
    float4 v = *(const float4*)(src + (size_t)(r0 + row) * C + c0 + q4);
    tile[row][q4 + 0] = v.x; tile[row][q4 + 1] = v.y;
    tile[row][q4 + 2] = v.z; tile[row][q4 + 3] = v.w;
  }
  __syncthreads();
#pragma unroll
  for (int i = 0; i < 2; i++) {
    int idx = i * 256 + tid;
    int c = idx >> 3, r8 = (idx & 7) * 8;
    bf16x8_t ov;
#pragma unroll
    for (int j = 0; j < 8; j++) ov[j] = (__bf16)tile[r8 + j][c];
    *(bf16x8_t*)(dst + (size_t)(c0 + c) * R + r0 + r8) = ov;
  }
}

// ---------------- single transpose (LM head, once) ----------------
__global__ void transpose_kernel(const float* __restrict__ in, bf16_t* __restrict__ out,
                                 int R, int C) {
  __shared__ float tile[32][33];
  int r0 = blockIdx.y * 32, c0 = blockIdx.x * 32;
  int tx = threadIdx.x, ty = threadIdx.y;
  for (int i = 0; i < 4; i++)
    tile[ty + i * 8][tx] = in[(size_t)(r0 + ty + i * 8) * C + (c0 + tx)];
  __syncthreads();
  for (int i = 0; i < 4; i++)
    out[(size_t)(c0 + ty + i * 8) * R + (r0 + tx)] = f2b(tile[tx][ty + i * 8]);
}

enum { MODE_F32 = 0, MODE_BF16 = 1, MODE_QKV = 2, MODE_BF16R = 3 };

__device__ __forceinline__ void gload16(const bf16_t* g, bf16_t* l) {
  __builtin_amdgcn_global_load_lds((const __attribute__((address_space(1))) void*)g,
                                   (__attribute__((address_space(3))) void*)l, 16, 0, 0);
}

// bijective XCD-aware swizzle (m204)
__device__ __forceinline__ int xcd_swz(int flat, int nwg) {
  int q = nwg >> 3, r = nwg & 7;
  int xcd = flat & 7, idx = flat >> 3;
  return (xcd < r ? xcd * (q + 1) : r * (q + 1) + (xcd - r) * q) + idx;
}

// ---------------- gemm97: 128x128, BK=32, 4 waves, dbuf+prefetch ----------
#define BK 32
template <int BM, int BN, int MODE>
__global__ __launch_bounds__(256) void gemm97_kernel(
    const bf16_t* __restrict__ A, long long sAz, int lda,
    const bf16_t* __restrict__ Bt, long long sBz, int ldb,
    void* __restrict__ C, long long sCz,
    const float* __restrict__ bias,
    const void* __restrict__ resid,
    int M, int N, int K, int relu) {
  constexpr int FR = BM / 32, FC = BN / 32;
  constexpr int A_ISS = BM / 64, B_ISS = BN / 64;
  __shared__ __align__(16) bf16_t As[2][BM * BK];
  __shared__ __align__(16) bf16_t Bs[2][BN * BK];
  int tid = threadIdx.x;
  int z = blockIdx.z;
  int nwg = gridDim.x * gridDim.y;
  int flat = xcd_swz(blockIdx.y * gridDim.x + blockIdx.x, nwg);
  int m0 = (flat / gridDim.x) * BM, n0 = (flat % gridDim.x) * BN;
  const bf16_t* Ab = A + (size_t)z * sAz + (size_t)m0 * lda;
  const bf16_t* Bb = Bt + (size_t)z * sBz + (size_t)n0 * ldb;
  int lane = tid & 63, wave = tid >> 6;
  int wr = (wave >> 1) * (BM / 2), wc = (wave & 1) * (BN / 2);
  int lr = lane & 15, lk = (lane >> 4) * 8;
  int srow = tid >> 2;
  int scol = (tid & 3) * 8;

  f32x4_t acc[FR][FC];
  for (int i = 0; i < FR; i++)
    for (int j = 0; j < FC; j++)
      acc[i][j] = (f32x4_t){0.f, 0.f, 0.f, 0.f};

  auto stage = [&](int buf, int k0) {
#pragma unroll
    for (int i = 0; i < A_ISS; i++)
      gload16(Ab + (size_t)(i * 64 + srow) * lda + k0 + scol, &As[buf][i * 2048 + wave * 512]);
#pragma unroll
    for (int i = 0; i < B_ISS; i++)
      gload16(Bb + (size_t)(i * 64 + srow) * ldb + k0 + scol, &Bs[buf][i * 2048 + wave * 512]);
  };

  int nk = K / BK;
  stage(0, 0);
  __syncthreads();
  int cur = 0;
  for (int kt = 0; kt < nk; ++kt) {
    if (kt + 1 < nk) stage(cur ^ 1, (kt + 1) * BK);
    bf16x8_t af[FR], bfv[FC];
#pragma unroll
    for (int i = 0; i < FR; i++)
      af[i] = *(const bf16x8_t*)(&As[cur][(wr + i * 16 + lr) * BK + lk]);
#pragma unroll
    for (int j = 0; j < FC; j++)
      bfv[j] = *(const bf16x8_t*)(&Bs[cur][(wc + j * 16 + lr) * BK + lk]);
#pragma unroll
    for (int i = 0; i < FR; i++)
#pragma unroll
      for (int j = 0; j < FC; j++)
        acc[i][j] = __builtin_amdgcn_mfma_f32_16x16x32_bf16(af[i], bfv[j], acc[i][j], 0, 0, 0);
    __syncthreads();
    cur ^= 1;
  }

#pragma unroll
  for (int i = 0; i < FR; i++)
#pragma unroll
    for (int j = 0; j < FC; j++) {
      f32x4_t v = acc[i][j];
      int n = n0 + wc + j * 16 + lr;
      int mb = m0 + wr + i * 16 + (lane >> 4) * 4;
#pragma unroll
      for (int r = 0; r < 4; r++) {
        int m = mb + r;
        float val = v[r];
        if (bias) val += bias[n];
        if (relu) val = fmaxf(val, 0.f);
        if (MODE == MODE_F32) {
          size_t idx = (size_t)z * sCz + (size_t)m * N + n;
          ((float*)C)[idx] = val;
        } else if (MODE == MODE_BF16) {
          size_t idx = (size_t)z * sCz + (size_t)m * N + n;
          ((bf16_t*)C)[idx] = f2b(val);
        } else if (MODE == MODE_BF16R) {
          size_t idx = (size_t)m * N + n;
          val += __bfloat162float(((const bf16_t*)resid)[idx]);
          ((bf16_t*)C)[idx] = f2b(val);
        } else { // MODE_QKV
          int sect = n >> 10, hd = n & 1023, h = hd >> 6, d = hd & 63;
          int b = m >> 10, t = m & 1023;
          size_t base = (size_t)sect * ((size_t)B_ * H_ * T_ * D_);
          size_t idx = base + ((size_t)(b * H_ + h) << 16) +
                       (sect == 2 ? (size_t)((d << 10) + t) : (size_t)((t << 6) + d));
          ((bf16_t*)C)[idx] = f2b(val);
        }
      }
    }
}

// ---------------- gemm3: 256x128, BK=64, 8 waves, triple-buffer + counted vmcnt ----------
template <int MODE>
__global__ __launch_bounds__(512) void gemm3_kernel(
    const bf16_t* __restrict__ A, int lda,
    const bf16_t* __restrict__ Bt, int ldb,
    void* __restrict__ C, long long sCz,
    const float* __restrict__ bias,
    int M, int N, int kspan, int relu) {
  constexpr int ABUFE = 256 * 64;
  constexpr int BBUFE = 128 * 64;
  __shared__ __align__(16) bf16_t LA[3 * ABUFE];
  __shared__ __align__(16) bf16_t LB[3 * BBUFE];
  int tid = threadIdx.x, lane = tid & 63, wave = tid >> 6;
  int wm = wave >> 1, wn = wave & 1;
  int z = blockIdx.z;
  int nwg = gridDim.x * gridDim.y;
  int flat = xcd_swz(blockIdx.y * gridDim.x + blockIdx.x, nwg);
  int m0 = (flat / gridDim.x) * 256, n0 = (flat % gridDim.x) * 128;
  const bf16_t* Ab = A + (size_t)m0 * lda + (size_t)z * kspan;
  const bf16_t* Bb = Bt + (size_t)n0 * ldb + (size_t)z * kspan;
  int sr = lane & 15, sc = (lane >> 4) * 8;

  f32x4_t acc[4][4];
#pragma unroll
  for (int i = 0; i < 4; i++)
#pragma unroll
    for (int j = 0; j < 4; j++)
      acc[i][j] = (f32x4_t){0.f, 0.f, 0.f, 0.f};

  auto stageh = [&](int b, int kt, int h) {
    int kg = kt * 64;
#pragma unroll
    for (int ch = 0; ch < 2; ch++) {
      int sub = wave * 4 + 2 * h + ch;
      gload16(Ab + (size_t)((sub >> 1) * 16 + sr) * lda + kg + (sub & 1) * 32 + sc,
              LA + b * ABUFE + sub * 512);
    }
    {
      int sub = wave * 2 + h;
      gload16(Bb + (size_t)((sub >> 1) * 16 + sr) * ldb + kg + (sub & 1) * 32 + sc,
              LB + b * BBUFE + sub * 512);
    }
  };

  auto phase = [&](int b, int ks, int t, int nk) {
    bf16x8_t af[4], bfv[4];
    unsigned abase = (unsigned)(size_t)(LA + b * ABUFE);
    unsigned bbase = (unsigned)(size_t)(LB + b * BBUFE);
#pragma unroll
    for (int i = 0; i < 4; i++) {
      unsigned ad = abase + (unsigned)((((wm * 4 + i) * 2 + ks) * 512 + lane * 8) * 2);
      asm volatile("ds_read_b128 %0, %1" : "=v"(af[i]) : "v"(ad));
    }
#pragma unroll
    for (int j = 0; j < 4; j++) {
      unsigned bd = bbase + (unsigned)((((wn * 4 + j) * 2 + ks) * 512 + lane * 8) * 2);
      asm volatile("ds_read_b128 %0, %1" : "=v"(bfv[j]) : "v"(bd));
    }
    if (t + 2 < nk) stageh((t + 2) % 3, t + 2, ks);
    __builtin_amdgcn_s_barrier();
    asm volatile("s_waitcnt lgkmcnt(0)" ::: "memory");
    __builtin_amdgcn_sched_barrier(0);
    __builtin_amdgcn_s_setprio(1);
#pragma unroll
    for (int i = 0; i < 4; i++)
#pragma unroll
      for (int j = 0; j < 4; j++)
        acc[i][j] = __builtin_amdgcn_mfma_f32_16x16x32_bf16(af[i], bfv[j], acc[i][j], 0, 0, 0);
    __builtin_amdgcn_s_setprio(0);
  };

  int nk = kspan / 64;
  stageh(0, 0, 0); stageh(0, 0, 1);
  stageh(1, 1, 0); stageh(1, 1, 1);
  for (int t = 0; t < nk; ++t) {
    int b = t % 3;
    if (t + 1 < nk) { asm volatile("s_waitcnt vmcnt(6)" ::: "memory"); }
    else            { asm volatile("s_waitcnt vmcnt(0)" ::: "memory"); }
    __builtin_amdgcn_s_barrier();
    phase(b, 0, t, nk);
    phase(b, 1, t, nk);
  }

#pragma unroll
  for (int i = 0; i < 4; i++)
#pragma unroll
    for (int j = 0; j < 4; j++) {
      f32x4_t v = acc[i][j];
      int n = n0 + wn * 64 + j * 16 + (lane & 15);
      int mb = m0 + wm * 64 + i * 16 + (lane >> 4) * 4;
#pragma unroll
      for (int r = 0; r < 4; r++) {
        int m = mb + r;
        float val = v[r];
        if (bias) val += bias[n];
        if (relu) val = fmaxf(val, 0.f);
        if (MODE == MODE_F32) {
          size_t idx = (size_t)z * sCz + (size_t)m * N + n;
          ((float*)C)[idx] = val;
        } else {
          size_t idx = (size_t)z * sCz + (size_t)m * N + n;
          ((bf16_t*)C)[idx] = f2b(val);
        }
      }
    }
}

// ---------------- flash attention: QBLK=64, 4 waves, defer-max (T13) + setprio (T5) ----------
#define KPAD 72

__global__ __launch_bounds__(256) void flash_kernel(
    const bf16_t* __restrict__ q,
    const bf16_t* __restrict__ kk,
    const bf16_t* __restrict__ vt,
    bf16_t* __restrict__ o) {
  __shared__ __align__(16) bf16_t Ks[64 * KPAD];
  __shared__ __align__(16) bf16_t Vs[64 * KPAD];
  __shared__ __align__(16) bf16_t Ps[4][16 * KPAD];
  int bid = blockIdx.x;
  int qi = 15 - (bid >> 6);
  int bh = bid & 63;
  int b = bh >> 4, h = bh & 15;
  const bf16_t* qb = q + ((size_t)bh << 16);
  const bf16_t* kb = kk + ((size_t)bh << 16);
  const bf16_t* vb = vt + ((size_t)bh << 16);
  int tid = threadIdx.x, lane = tid & 63, wave = tid >> 6;
  int lr = lane & 15, lg = lane >> 4;
  int qbase = qi * 64;

  bf16x8_t qf[2];
  {
    const bf16_t* qrow = qb + (size_t)(qbase + wave * 16 + lr) * D_ + lg * 8;
    qf[0] = *(const bf16x8_t*)(qrow);
    qf[1] = *(const bf16x8_t*)(qrow + 32);
  }

  float m_r[4], l_r[4];
  f32x4_t oc[4];
#pragma unroll
  for (int r = 0; r < 4; r++) { m_r[r] = -1e30f; l_r[r] = 0.f; }
#pragma unroll
  for (int j = 0; j < 4; j++) oc[j] = (f32x4_t){0.f, 0.f, 0.f, 0.f};

  int srow = tid >> 2, scol = (tid & 3) * 16;

  bf16x8_t k0, k1, v0, v1;
  {
    const bf16_t* kg = kb + (size_t)srow * D_ + scol;
    k0 = *(const bf16x8_t*)kg;
    k1 = *(const bf16x8_t*)(kg + 8);
    const bf16_t* vg = vb + (size_t)srow * T_ + scol;
    v0 = *(const bf16x8_t*)vg;
    v1 = *(const bf16x8_t*)(vg + 8);
  }

  for (int s = 0; s <= qi; s++) {
    __syncthreads();
    *(bf16x8_t*)(&Ks[srow * KPAD + scol]) = k0;
    *(bf16x8_t*)(&Ks[srow * KPAD + scol + 8]) = k1;
    *(bf16x8_t*)(&Vs[srow * KPAD + scol]) = v0;
    *(bf16x8_t*)(&Vs[srow * KPAD + scol + 8]) = v1;
    __syncthreads();

    if (s < qi) {
      int kv1 = (s + 1) * 64;
      const bf16_t* kg = kb + (size_t)(kv1 + srow) * D_ + scol;
      k0 = *(const bf16x8_t*)kg;
      k1 = *(const bf16x8_t*)(kg + 8);
      const bf16_t* vg = vb + (size_t)srow * T_ + kv1 + scol;
      v0 = *(const bf16x8_t*)vg;
      v1 = *(const bf16x8_t*)(vg + 8);
    }

    int kv0 = s * 64;
    f32x4_t sc[4];
    __builtin_amdgcn_s_setprio(1);
#pragma unroll
    for (int j = 0; j < 4; j++) {
      f32x4_t a = (f32x4_t){0.f, 0.f, 0.f, 0.f};
      bf16x8_t b0 = *(const bf16x8_t*)(&Ks[(j * 16 + lr) * KPAD + lg * 8]);
      bf16x8_t b1 = *(const bf16x8_t*)(&Ks[(j * 16 + lr) * KPAD + lg * 8 + 32]);
      a = __builtin_amdgcn_mfma_f32_16x16x32_bf16(qf[0], b0, a, 0, 0, 0);
      a = __builtin_amdgcn_mfma_f32_16x16x32_bf16(qf[1], b1, a, 0, 0, 0);
      sc[j] = a;
    }
    __builtin_amdgcn_s_setprio(0);
    if (s == qi) {
#pragma unroll
      for (int j = 0; j < 4; j++)
#pragma unroll
        for (int r = 0; r < 4; r++) {
          int kvp = kv0 + j * 16 + lr;
          int qp  = qbase + wave * 16 + lg * 4 + r;
          sc[j][r] = (kvp <= qp) ? sc[j][r] * 0.125f : -1e30f;
        }
    } else {
#pragma unroll
      for (int j = 0; j < 4; j++)
#pragma unroll
        for (int r = 0; r < 4; r++) sc[j][r] *= 0.125f;
    }

    float pm[4];
#pragma unroll
    for (int r = 0; r < 4; r++) {
      float v = fmaxf(fmaxf(sc[0][r], sc[1][r]), fmaxf(sc[2][r], sc[3][r]));
      v = fmaxf(v, __shfl_xor(v, 1, 64));
      v = fmaxf(v, __shfl_xor(v, 2, 64));
      v = fmaxf(v, __shfl_xor(v, 4, 64));
      v = fmaxf(v, __shfl_xor(v, 8, 64));
      pm[r] = v;
    }
    bool ok = (pm[0] - m_r[0] <= 8.f) && (pm[1] - m_r[1] <= 8.f) &&
              (pm[2] - m_r[2] <= 8.f) && (pm[3] - m_r[3] <= 8.f);
    if (!__all(ok)) {
#pragma unroll
      for (int r = 0; r < 4; r++) {
        float mn = fmaxf(m_r[r], pm[r]);
        float ex = __expf(m_r[r] - mn);
        m_r[r] = mn;
        l_r[r] *= ex;
#pragma unroll
        for (int j = 0; j < 4; j++) oc[j][r] *= ex;
      }
    }
#pragma unroll
    for (int j = 0; j < 4; j++)
#pragma unroll
      for (int r = 0; r < 4; r++) {
        float p = __expf(sc[j][r] - m_r[r]);
        l_r[r] += p;
        Ps[wave][(lg * 4 + r) * KPAD + j * 16 + lr] = f2b(p);
      }

    bf16x8_t pa0 = *(const bf16x8_t*)(&Ps[wave][lr * KPAD + lg * 8]);
    bf16x8_t pa1 = *(const bf16x8_t*)(&Ps[wave][lr * KPAD + lg * 8 + 32]);
    __builtin_amdgcn_s_setprio(1);
#pragma unroll
    for (int j = 0; j < 4; j++) {
      bf16x8_t vb0 = *(const bf16x8_t*)(&Vs[(j * 16 + lr) * KPAD + lg * 8]);
      bf16x8_t vb1 = *(const bf16x8_t*)(&Vs[(j * 16 + lr) * KPAD + lg * 8 + 32]);
      oc[j] = __builtin_amdgcn_mfma_f32_16x16x32_bf16(pa0, vb0, oc[j], 0, 0, 0);
      oc[j] = __builtin_amdgcn_mfma_f32_16x16x32_bf16(pa1, vb1, oc[j], 0, 0, 0);
    }
    __builtin_amdgcn_s_setprio(0);
  }

#pragma unroll
  for (int r = 0; r < 4; r++) {
    float v = l_r[r];
    v += __shfl_xor(v, 1, 64);
    v += __shfl_xor(v, 2, 64);
    v += __shfl_xor(v, 4, 64);
    v += __shfl_xor(v, 8, 64);
    l_r[r] = 1.f / v;
  }
  bf16_t* ob = o + ((size_t)(b * T_ + qbase + wave * 16)) * (H_ * D_) + h * D_;
#pragma unroll
  for (int j = 0; j < 4; j++)
#pragma unroll
    for (int r = 0; r < 4; r++) {
      int qrow = lg * 4 + r;
      ob[(size_t)qrow * (H_ * D_) + j * 16 + lr] = f2b(oc[j][r] * l_r[r]);
    }
}

// ---------------- host launch ----------------
extern "C" void kernel_launch(void* const* d_in, const int* in_sizes, int n_in,
                              void* d_out, int out_size, void* d_ws, size_t ws_size,
                              hipStream_t stream) {
  (void)in_sizes; (void)n_in; (void)out_size; (void)ws_size;
  const int*   tokens = (const int*)d_in[0];
  const float* tok_emb = (const float*)d_in[1];
  const float* pos_emb = (const float*)d_in[2];
  const float* Wq = (const float*)d_in[3];
  const float* Wk = (const float*)d_in[4];
  const float* Wv = (const float*)d_in[5];
  const float* Wo = (const float*)d_in[6];
  const float* bo = (const float*)d_in[7];
  const float* ln1_g = (const float*)d_in[8];
  const float* ln1_b = (const float*)d_in[9];
  const float* ln2_g = (const float*)d_in[10];
  const float* ln2_b = (const float*)d_in[11];
  const float* W1 = (const float*)d_in[12];
  const float* b1 = (const float*)d_in[13];
  const float* W2 = (const float*)d_in[14];
  const float* b2 = (const float*)d_in[15];
  const float* lnf_g = (const float*)d_in[16];
  const float* lnf_b = (const float*)d_in[17];
  const float* Wlm = (const float*)d_in[18];
  const float* blm = (const float*)d_in[19];

  char* w = (char*)d_ws;
  size_t off = 0;
  auto alloc = [&](size_t bytes) { void* p = (void*)(w + off); off += (bytes + 255) & ~(size_t)255; return p; };
  bf16_t* r    = (bf16_t*)alloc((size_t)MTOK * E_ * 2);
  bf16_t* t    = (bf16_t*)alloc((size_t)MTOK * E_ * 2);
  bf16_t* q    = (bf16_t*)alloc((size_t)B_ * H_ * T_ * D_ * 2);
  bf16_t* kk   = (bf16_t*)alloc((size_t)B_ * H_ * T_ * D_ * 2);
  bf16_t* vt   = (bf16_t*)alloc((size_t)B_ * H_ * T_ * D_ * 2);
  bf16_t* o    = (bf16_t*)alloc((size_t)MTOK * E_ * 2);
  bf16_t* h1   = (bf16_t*)alloc((size_t)MTOK * FF_ * 2);
  bf16_t* WqkvT = (bf16_t*)alloc((size_t)3 * E_ * H_ * D_ * 2);
  bf16_t* WoT  = (bf16_t*)alloc((size_t)E_ * H_ * D_ * 2);
  bf16_t* W1T  = (bf16_t*)alloc((size_t)E_ * FF_ * 2);
  bf16_t* W2T  = (bf16_t*)alloc((size_t)E_ * FF_ * 2);
  bf16_t* WlmT = (bf16_t*)alloc((size_t)E_ * V_ * 2);
  bf16_t* p2   = (bf16_t*)alloc((size_t)2 * MTOK * E_ * 2);

  embed_kernel<<<MTOK, 256, 0, stream>>>(tokens, tok_emb, pos_emb, r);
  transpose_kernel<<<dim3(V_ / 32, E_ / 32), dim3(32, 8), 0, stream>>>(Wlm, WlmT, E_, V_);
  ln_kernel<<<MTOK / 2, 256, 0, stream>>>(r, t, ln1_g, ln1_b);

  for (int l = 0; l < LAYERS; l++) {
    prep_weights_kernel<<<3072, 256, 0, stream>>>(
        Wq, Wk, Wv, Wo, W1, W2, WqkvT, WoT, W1T, W2T, l);

    gemm97_kernel<128, 128, MODE_QKV><<<dim3(24, 32, 1), 256, 0, stream>>>(
        t, 0, E_, WqkvT, 0, E_, q, 0, nullptr, nullptr, MTOK, 3 * H_ * D_, E_, 0);

    flash_kernel<<<1024, 256, 0, stream>>>(q, kk, vt, o);

    gemm97_kernel<128, 128, MODE_BF16R><<<dim3(8, 32, 1), 256, 0, stream>>>(
        o, 0, H_ * D_, WoT, 0, H_ * D_, r, 0, bo + l * E_, t, MTOK, E_, H_ * D_, 0);

    ln_kernel<<<MTOK / 2, 256, 0, stream>>>(r, t, ln2_g + l * E_, ln2_b + l * E_);

    gemm3_kernel<MODE_BF16><<<dim3(32, 16, 1), 512, 0, stream>>>(
        t, E_, W1T, E_, h1, 0, b1 + l * FF_, MTOK, FF_, E_, 1);
    gemm3_kernel<MODE_BF16><<<dim3(8, 16, 2), 512, 0, stream>>>(
        h1, FF_, W2T, FF_, p2, (long long)MTOK * E_, nullptr, MTOK, E_, FF_ / 2, 0);
    const float* gn = (l + 1 < LAYERS) ? (ln1_g + (l + 1) * E_) : lnf_g;
    const float* bn = (l + 1 < LAYERS) ? (ln1_b + (l + 1) * E_) : lnf_b;
    reduce_ln_kernel<<<MTOK / 2, 256, 0, stream>>>(p2, t, b2 + l * E_, r, t, gn, bn);
  }

  gemm3_kernel<MODE_F32><<<dim3(16, 16, 1), 512, 0, stream>>>(
      t, E_, WlmT, E_, d_out, 0, blm, MTOK, V_, E_, 0);
}

// Round 17
// 2063.347 us; speedup vs baseline: 1.0169x; 1.0062x over previous
//
#include <hip/hip_runtime.h>
#include <hip/hip_bf16.h>

#define LAYERS 8
#define H_ 16
#define E_ 1024
#define D_ 64
#define FF_ 4096
#define V_ 2048
#define B_ 4
#define T_ 1024
#define MTOK (B_*T_)

typedef __bf16 bf16x8_t __attribute__((ext_vector_type(8)));
typedef __bf16 bf16x4_t __attribute__((ext_vector_type(4)));
typedef float f32x4_t __attribute__((ext_vector_type(4)));
typedef __hip_bfloat16 bf16_t;

__device__ __forceinline__ bf16_t f2b(float f) { return __float2bfloat16(f); }

// ---------------- fused embedding + ln1(layer0): r = bf16(te[tok]+pe[tok]); t = ln(r) --------
__global__ __launch_bounds__(256) void embed_ln_kernel(const int* __restrict__ tokens,
                                                       const float* __restrict__ te,
                                                       const float* __restrict__ pe,
                                                       bf16_t* __restrict__ r,
                                                       bf16_t* __restrict__ t,
                                                       const float* __restrict__ g,
                                                       const float* __restrict__ b) {
  int row = blockIdx.x, tid = threadIdx.x;
  int tok = tokens[row];
  float4 va = ((const float4*)(te + (size_t)tok * E_))[tid];
  float4 vp = ((const float4*)(pe + (size_t)tok * E_))[tid];
  bf16x4_t rv;
  rv[0] = (__bf16)(va.x + vp.x); rv[1] = (__bf16)(va.y + vp.y);
  rv[2] = (__bf16)(va.z + vp.z); rv[3] = (__bf16)(va.w + vp.w);
  ((bf16x4_t*)(r + (size_t)row * E_))[tid] = rv;
  float z0 = (float)rv[0], z1 = (float)rv[1], z2 = (float)rv[2], z3 = (float)rv[3];
  float s = z0 + z1 + z2 + z3, sq = z0*z0 + z1*z1 + z2*z2 + z3*z3;
  for (int off = 32; off; off >>= 1) {
    s  += __shfl_xor(s, off, 64);
    sq += __shfl_xor(sq, off, 64);
  }
  __shared__ float2 wred[4];
  if ((tid & 63) == 0) wred[tid >> 6] = make_float2(s, sq);
  __syncthreads();
  float2 w0 = wred[0], w1 = wred[1], w2 = wred[2], w3 = wred[3];
  float S = w0.x + w1.x + w2.x + w3.x, SQ = w0.y + w1.y + w2.y + w3.y;
  float mean = S * (1.0f / E_);
  float var  = SQ * (1.0f / E_) - mean * mean;
  float inv = rsqrtf(var + 1e-5f);
  float4 gv = ((const float4*)g)[tid];
  float4 bv = ((const float4*)b)[tid];
  bf16x4_t o;
  o[0] = (__bf16)((z0 - mean) * inv * gv.x + bv.x);
  o[1] = (__bf16)((z1 - mean) * inv * gv.y + bv.y);
  o[2] = (__bf16)((z2 - mean) * inv * gv.z + bv.z);
  o[3] = (__bf16)((z3 - mean) * inv * gv.w + bv.w);
  ((bf16x4_t*)(t + (size_t)row * E_))[tid] = o;
}

// ---------------- layernorm: 2 rows/block, 128 thr/row, bf16x8 ----------------
__global__ __launch_bounds__(256) void ln_kernel(const bf16_t* __restrict__ xin,
                                                 bf16_t* __restrict__ xout,
                                                 const float* __restrict__ g,
                                                 const float* __restrict__ b) {
  int tid = threadIdx.x;
  int row = blockIdx.x * 2 + (tid >> 7);
  int li = tid & 127;
  size_t base = (size_t)row * E_ + li * 8;
  bf16x8_t v8 = *(const bf16x8_t*)(xin + base);
  float z[8];
  float s = 0.f, sq = 0.f;
#pragma unroll
  for (int j = 0; j < 8; j++) { z[j] = (float)v8[j]; s += z[j]; sq += z[j] * z[j]; }
  for (int off = 32; off; off >>= 1) {
    s  += __shfl_xor(s, off, 64);
    sq += __shfl_xor(sq, off, 64);
  }
  __shared__ float2 wred[4];
  if ((tid & 63) == 0) wred[tid >> 6] = make_float2(s, sq);
  __syncthreads();
  int wb = (tid >> 7) << 1;
  float S = wred[wb].x + wred[wb + 1].x, SQ = wred[wb].y + wred[wb + 1].y;
  float mean = S * (1.0f / E_);
  float var  = SQ * (1.0f / E_) - mean * mean;
  float inv = rsqrtf(var + 1e-5f);
  float4 g0 = *(const float4*)(g + li * 8), g1 = *(const float4*)(g + li * 8 + 4);
  float4 b0 = *(const float4*)(b + li * 8), b1 = *(const float4*)(b + li * 8 + 4);
  float gg[8] = {g0.x, g0.y, g0.z, g0.w, g1.x, g1.y, g1.z, g1.w};
  float bb[8] = {b0.x, b0.y, b0.z, b0.w, b1.x, b1.y, b1.z, b1.w};
  bf16x8_t o;
#pragma unroll
  for (int j = 0; j < 8; j++) o[j] = (__bf16)((z[j] - mean) * inv * gg[j] + bb[j]);
  *(bf16x8_t*)(xout + base) = o;
}

// ---------------- fused split-K reduce + LayerNorm: 2 rows/block, bf16x8 ----------------
__global__ __launch_bounds__(256) void reduce_ln_kernel(
    const bf16_t* __restrict__ p,
    const bf16_t* __restrict__ tin,
    const float* __restrict__ bias,
    bf16_t* __restrict__ r,
    bf16_t* __restrict__ tout,
    const float* __restrict__ g,
    const float* __restrict__ b) {
  int tid = threadIdx.x;
  int row = blockIdx.x * 2 + (tid >> 7);
  int li = tid & 127;
  size_t base = (size_t)row * E_ + li * 8;
  bf16x8_t tv = *(const bf16x8_t*)(tin + base);
  bf16x8_t p0 = *(const bf16x8_t*)(p + base);
  bf16x8_t p1 = *(const bf16x8_t*)(p + (size_t)MTOK * E_ + base);
  float4 c0 = *(const float4*)(bias + li * 8), c1 = *(const float4*)(bias + li * 8 + 4);
  float bb[8] = {c0.x, c0.y, c0.z, c0.w, c1.x, c1.y, c1.z, c1.w};
  bf16x8_t rv;
  float z[8];
  float s = 0.f, sq = 0.f;
#pragma unroll
  for (int j = 0; j < 8; j++) {
    float y = (float)tv[j] + (float)p0[j] + (float)p1[j] + bb[j];
    rv[j] = (__bf16)y;
    z[j] = (float)rv[j];
    s += z[j]; sq += z[j] * z[j];
  }
  *(bf16x8_t*)(r + base) = rv;
  for (int off = 32; off; off >>= 1) {
    s  += __shfl_xor(s, off, 64);
    sq += __shfl_xor(sq, off, 64);
  }
  __shared__ float2 wred[4];
  if ((tid & 63) == 0) wred[tid >> 6] = make_float2(s, sq);
  __syncthreads();
  int wb = (tid >> 7) << 1;
  float S = wred[wb].x + wred[wb + 1].x, SQ = wred[wb].y + wred[wb + 1].y;
  float mean = S * (1.0f / E_);
  float var  = SQ * (1.0f / E_) - mean * mean;
  float inv = rsqrtf(var + 1e-5f);
  float4 g0 = *(const float4*)(g + li * 8), g1 = *(const float4*)(g + li * 8 + 4);
  float4 d0 = *(const float4*)(b + li * 8), d1 = *(const float4*)(b + li * 8 + 4);
  float gg[8] = {g0.x, g0.y, g0.z, g0.w, g1.x, g1.y, g1.z, g1.w};
  float dd[8] = {d0.x, d0.y, d0.z, d0.w, d1.x, d1.y, d1.z, d1.w};
  bf16x8_t o;
#pragma unroll
  for (int j = 0; j < 8; j++) o[j] = (__bf16)((z[j] - mean) * inv * gg[j] + dd[j]);
  *(bf16x8_t*)(tout + base) = o;
}

// ---------------- fused per-layer weight transpose: 64x64 tiles, f32x4 read / bf16x8 write ----
__global__ __launch_bounds__(256) void prep_weights_kernel(
    const float* __restrict__ Wq, const float* __restrict__ Wk,
    const float* __restrict__ Wv, const float* __restrict__ Wo,
    const float* __restrict__ W1, const float* __restrict__ W2,
    bf16_t* __restrict__ WqkvT, bf16_t* __restrict__ WoT,
    bf16_t* __restrict__ W1T, bf16_t* __restrict__ W2T, int l) {
  __shared__ float tile[64][65];
  int bid = blockIdx.x, tid = threadIdx.x;
  const float* src; bf16_t* dst; int R, C, r0, c0;
  if (bid < 768) {
    int op = bid >> 8, rem = bid & 255;
    int h = rem >> 4, tt = rem & 15;
    const float* W = (op == 0) ? Wq : (op == 1) ? Wk : Wv;
    src = W + (size_t)l * H_ * E_ * D_ + (size_t)h * E_ * D_;
    dst = WqkvT + (size_t)op * E_ * H_ * D_ + (size_t)h * E_ * D_;
    R = E_; C = D_; r0 = tt * 64; c0 = 0;
  } else if (bid < 1024) {
    int tt = bid - 768;
    src = Wo + (size_t)l * H_ * D_ * E_; dst = WoT;
    R = H_ * D_; C = E_; r0 = (tt >> 4) * 64; c0 = (tt & 15) * 64;
  } else if (bid < 2048) {
    int tt = bid - 1024;
    src = W1 + (size_t)l * E_ * FF_; dst = W1T;
    R = E_; C = FF_; r0 = (tt >> 6) * 64; c0 = (tt & 63) * 64;
  } else {
    int tt = bid - 2048;
    src = W2 + (size_t)l * FF_ * E_; dst = W2T;
    R = FF_; C = E_; r0 = (tt >> 4) * 64; c0 = (tt & 15) * 64;
  }
#pragma unroll
  for (int i = 0; i < 4; i++) {
    int idx = i * 256 + tid;
    int row = idx >> 4, q4 = (idx & 15) * 4;
    float4 v = *(const float4*)(src + (size_t)(r0 + row) * C + c0 + q4);
    tile[row][q4 + 0] = v.x; tile[row][q4 + 1] = v.y;
    tile[row][q4 + 2] = v.z; tile[row][q4 + 3] = v.w;
  }
  __syncthreads();
#pragma unroll
  for (int i = 0; i < 2; i++) {
    int idx = i * 256 + tid;
    int c = idx >> 3, r8 = (idx & 7) * 8;
    bf16x8_t ov;
#pragma unroll
    for (int j = 0; j < 8; j++) ov[j] = (__bf16)tile[r8 + j][c];
    *(bf16x8_t*)(dst + (size_t)(c0 + c) * R + r0 + r8) = ov;
  }
}

// ---------------- single transpose (LM head, once) ----------------
__global__ void transpose_kernel(const float* __restrict__ in, bf16_t* __restrict__ out,
                                 int R, int C) {
  __shared__ float tile[32][33];
  int r0 = blockIdx.y * 32, c0 = blockIdx.x * 32;
  int tx = threadIdx.x, ty = threadIdx.y;
  for (int i = 0; i < 4; i++)
    tile[ty + i * 8][tx] = in[(size_t)(r0 + ty + i * 8) * C + (c0 + tx)];
  __syncthreads();
  for (int i = 0; i < 4; i++)
    out[(size_t)(c0 + ty + i * 8) * R + (r0 + tx)] = f2b(tile[tx][ty + i * 8]);
}

// ---------------- v [B,H,T,D] -> vt [B,H,D,T], 64x64 LDS tiles, bf16x8 both sides ----------
__global__ __launch_bounds__(256) void transpose_v_kernel(const bf16_t* __restrict__ v,
                                                          bf16_t* __restrict__ vt) {
  __shared__ bf16_t tile[64][72];
  int bh = blockIdx.y;
  int t0 = blockIdx.x * 64;
  const bf16_t* src = v + ((size_t)bh << 16);
  bf16_t* dst = vt + ((size_t)bh << 16);
  int tid = threadIdx.x;
  int row = tid >> 2, c0 = (tid & 3) * 16;   // row = t offset, c0 = d offset
  bf16x8_t a0 = *(const bf16x8_t*)(src + (size_t)(t0 + row) * D_ + c0);
  bf16x8_t a1 = *(const bf16x8_t*)(src + (size_t)(t0 + row) * D_ + c0 + 8);
  *(bf16x8_t*)(&tile[row][c0]) = a0;
  *(bf16x8_t*)(&tile[row][c0 + 8]) = a1;
  __syncthreads();
  int drow = tid >> 2, tc0 = (tid & 3) * 16;
  bf16x8_t o0, o1;
#pragma unroll
  for (int j = 0; j < 8; j++) o0[j] = tile[tc0 + j][drow];
#pragma unroll
  for (int j = 0; j < 8; j++) o1[j] = tile[tc0 + 8 + j][drow];
  *(bf16x8_t*)(dst + (size_t)drow * T_ + t0 + tc0) = o0;
  *(bf16x8_t*)(dst + (size_t)drow * T_ + t0 + tc0 + 8) = o1;
}

enum { MODE_F32 = 0, MODE_BF16 = 1, MODE_QKV = 2, MODE_BF16R = 3 };

__device__ __forceinline__ void gload16(const bf16_t* g, bf16_t* l) {
  __builtin_amdgcn_global_load_lds((const __attribute__((address_space(1))) void*)g,
                                   (__attribute__((address_space(3))) void*)l, 16, 0, 0);
}

// bijective XCD-aware swizzle (m204)
__device__ __forceinline__ int xcd_swz(int flat, int nwg) {
  int q = nwg >> 3, r = nwg & 7;
  int xcd = flat & 7, idx = flat >> 3;
  return (xcd < r ? xcd * (q + 1) : r * (q + 1) + (xcd - r) * q) + idx;
}

// ---------------- gemm97: 128x128, BK=32, 4 waves, dbuf+prefetch ----------
#define BK 32
template <int BM, int BN, int MODE>
__global__ __launch_bounds__(256) void gemm97_kernel(
    const bf16_t* __restrict__ A, long long sAz, int lda,
    const bf16_t* __restrict__ Bt, long long sBz, int ldb,
    void* __restrict__ C, long long sCz,
    const float* __restrict__ bias,
    const void* __restrict__ resid,
    int M, int N, int K, int relu) {
  constexpr int FR = BM / 32, FC = BN / 32;
  constexpr int A_ISS = BM / 64, B_ISS = BN / 64;
  __shared__ __align__(16) bf16_t As[2][BM * BK];
  __shared__ __align__(16) bf16_t Bs[2][BN * BK];
  int tid = threadIdx.x;
  int z = blockIdx.z;
  int nwg = gridDim.x * gridDim.y;
  int flat = xcd_swz(blockIdx.y * gridDim.x + blockIdx.x, nwg);
  int m0 = (flat / gridDim.x) * BM, n0 = (flat % gridDim.x) * BN;
  const bf16_t* Ab = A + (size_t)z * sAz + (size_t)m0 * lda;
  const bf16_t* Bb = Bt + (size_t)z * sBz + (size_t)n0 * ldb;
  int lane = tid & 63, wave = tid >> 6;
  int wr = (wave >> 1) * (BM / 2), wc = (wave & 1) * (BN / 2);
  int lr = lane & 15, lk = (lane >> 4) * 8;
  int srow = tid >> 2;
  int scol = (tid & 3) * 8;

  f32x4_t acc[FR][FC];
  for (int i = 0; i < FR; i++)
    for (int j = 0; j < FC; j++)
      acc[i][j] = (f32x4_t){0.f, 0.f, 0.f, 0.f};

  auto stage = [&](int buf, int k0) {
#pragma unroll
    for (int i = 0; i < A_ISS; i++)
      gload16(Ab + (size_t)(i * 64 + srow) * lda + k0 + scol, &As[buf][i * 2048 + wave * 512]);
#pragma unroll
    for (int i = 0; i < B_ISS; i++)
      gload16(Bb + (size_t)(i * 64 + srow) * ldb + k0 + scol, &Bs[buf][i * 2048 + wave * 512]);
  };

  int nk = K / BK;
  stage(0, 0);
  __syncthreads();
  int cur = 0;
  for (int kt = 0; kt < nk; ++kt) {
    if (kt + 1 < nk) stage(cur ^ 1, (kt + 1) * BK);
    bf16x8_t af[FR], bfv[FC];
#pragma unroll
    for (int i = 0; i < FR; i++)
      af[i] = *(const bf16x8_t*)(&As[cur][(wr + i * 16 + lr) * BK + lk]);
#pragma unroll
    for (int j = 0; j < FC; j++)
      bfv[j] = *(const bf16x8_t*)(&Bs[cur][(wc + j * 16 + lr) * BK + lk]);
#pragma unroll
    for (int i = 0; i < FR; i++)
#pragma unroll
      for (int j = 0; j < FC; j++)
        acc[i][j] = __builtin_amdgcn_mfma_f32_16x16x32_bf16(af[i], bfv[j], acc[i][j], 0, 0, 0);
    __syncthreads();
    cur ^= 1;
  }

#pragma unroll
  for (int i = 0; i < FR; i++)
#pragma unroll
    for (int j = 0; j < FC; j++) {
      f32x4_t v = acc[i][j];
      int n = n0 + wc + j * 16 + lr;
      int mb = m0 + wr + i * 16 + (lane >> 4) * 4;
#pragma unroll
      for (int r = 0; r < 4; r++) {
        int m = mb + r;
        float val = v[r];
        if (bias) val += bias[n];
        if (relu) val = fmaxf(val, 0.f);
        if (MODE == MODE_F32) {
          size_t idx = (size_t)z * sCz + (size_t)m * N + n;
          ((float*)C)[idx] = val;
        } else if (MODE == MODE_BF16) {
          size_t idx = (size_t)z * sCz + (size_t)m * N + n;
          ((bf16_t*)C)[idx] = f2b(val);
        } else if (MODE == MODE_BF16R) {
          size_t idx = (size_t)m * N + n;
          val += __bfloat162float(((const bf16_t*)resid)[idx]);
          ((bf16_t*)C)[idx] = f2b(val);
        } else { // MODE_QKV: sect 0->q, 1->k, 2->v, all [B,H,T,D] (v transposed later)
          int sect = n >> 10, hd = n & 1023, h = hd >> 6, d = hd & 63;
          int b = m >> 10, t = m & 1023;
          size_t base = (size_t)sect * ((size_t)B_ * H_ * T_ * D_);
          size_t idx = base + ((size_t)(b * H_ + h) << 16) + (t << 6) + d;
          ((bf16_t*)C)[idx] = f2b(val);
        }
      }
    }
}

// ---------------- gemm3: 256x128, BK=64, 8 waves, triple-buffer + counted vmcnt ----------
template <int MODE>
__global__ __launch_bounds__(512) void gemm3_kernel(
    const bf16_t* __restrict__ A, int lda,
    const bf16_t* __restrict__ Bt, int ldb,
    void* __restrict__ C, long long sCz,
    const float* __restrict__ bias,
    int M, int N, int kspan, int relu) {
  constexpr int ABUFE = 256 * 64;
  constexpr int BBUFE = 128 * 64;
  __shared__ __align__(16) bf16_t LA[3 * ABUFE];
  __shared__ __align__(16) bf16_t LB[3 * BBUFE];
  int tid = threadIdx.x, lane = tid & 63, wave = tid >> 6;
  int wm = wave >> 1, wn = wave & 1;
  int z = blockIdx.z;
  int nwg = gridDim.x * gridDim.y;
  int flat = xcd_swz(blockIdx.y * gridDim.x + blockIdx.x, nwg);
  int m0 = (flat / gridDim.x) * 256, n0 = (flat % gridDim.x) * 128;
  const bf16_t* Ab = A + (size_t)m0 * lda + (size_t)z * kspan;
  const bf16_t* Bb = Bt + (size_t)n0 * ldb + (size_t)z * kspan;
  int sr = lane & 15, sc = (lane >> 4) * 8;

  f32x4_t acc[4][4];
#pragma unroll
  for (int i = 0; i < 4; i++)
#pragma unroll
    for (int j = 0; j < 4; j++)
      acc[i][j] = (f32x4_t){0.f, 0.f, 0.f, 0.f};

  auto stageh = [&](int b, int kt, int h) {
    int kg = kt * 64;
#pragma unroll
    for (int ch = 0; ch < 2; ch++) {
      int sub = wave * 4 + 2 * h + ch;
      gload16(Ab + (size_t)((sub >> 1) * 16 + sr) * lda + kg + (sub & 1) * 32 + sc,
              LA + b * ABUFE + sub * 512);
    }
    {
      int sub = wave * 2 + h;
      gload16(Bb + (size_t)((sub >> 1) * 16 + sr) * ldb + kg + (sub & 1) * 32 + sc,
              LB + b * BBUFE + sub * 512);
    }
  };

  auto phase = [&](int b, int ks, int t, int nk) {
    bf16x8_t af[4], bfv[4];
    unsigned abase = (unsigned)(size_t)(LA + b * ABUFE);
    unsigned bbase = (unsigned)(size_t)(LB + b * BBUFE);
#pragma unroll
    for (int i = 0; i < 4; i++) {
      unsigned ad = abase + (unsigned)((((wm * 4 + i) * 2 + ks) * 512 + lane * 8) * 2);
      asm volatile("ds_read_b128 %0, %1" : "=v"(af[i]) : "v"(ad));
    }
#pragma unroll
    for (int j = 0; j < 4; j++) {
      unsigned bd = bbase + (unsigned)((((wn * 4 + j) * 2 + ks) * 512 + lane * 8) * 2);
      asm volatile("ds_read_b128 %0, %1" : "=v"(bfv[j]) : "v"(bd));
    }
    if (t + 2 < nk) stageh((t + 2) % 3, t + 2, ks);
    __builtin_amdgcn_s_barrier();
    asm volatile("s_waitcnt lgkmcnt(0)" ::: "memory");
    __builtin_amdgcn_sched_barrier(0);
    __builtin_amdgcn_s_setprio(1);
#pragma unroll
    for (int i = 0; i < 4; i++)
#pragma unroll
      for (int j = 0; j < 4; j++)
        acc[i][j] = __builtin_amdgcn_mfma_f32_16x16x32_bf16(af[i], bfv[j], acc[i][j], 0, 0, 0);
    __builtin_amdgcn_s_setprio(0);
  };

  int nk = kspan / 64;
  stageh(0, 0, 0); stageh(0, 0, 1);
  stageh(1, 1, 0); stageh(1, 1, 1);
  for (int t = 0; t < nk; ++t) {
    int b = t % 3;
    if (t + 1 < nk) { asm volatile("s_waitcnt vmcnt(6)" ::: "memory"); }
    else            { asm volatile("s_waitcnt vmcnt(0)" ::: "memory"); }
    __builtin_amdgcn_s_barrier();
    phase(b, 0, t, nk);
    phase(b, 1, t, nk);
  }

#pragma unroll
  for (int i = 0; i < 4; i++)
#pragma unroll
    for (int j = 0; j < 4; j++) {
      f32x4_t v = acc[i][j];
      int n = n0 + wn * 64 + j * 16 + (lane & 15);
      int mb = m0 + wm * 64 + i * 16 + (lane >> 4) * 4;
#pragma unroll
      for (int r = 0; r < 4; r++) {
        int m = mb + r;
        float val = v[r];
        if (bias) val += bias[n];
        if (relu) val = fmaxf(val, 0.f);
        if (MODE == MODE_F32) {
          size_t idx = (size_t)z * sCz + (size_t)m * N + n;
          ((float*)C)[idx] = val;
        } else {
          size_t idx = (size_t)z * sCz + (size_t)m * N + n;
          ((bf16_t*)C)[idx] = f2b(val);
        }
      }
    }
}

// ---------------- flash attention: QBLK=64, 4 waves, defer-max (T13) + setprio (T5) ----------
#define KPAD 72

__global__ __launch_bounds__(256) void flash_kernel(
    const bf16_t* __restrict__ q,
    const bf16_t* __restrict__ kk,
    const bf16_t* __restrict__ vt,
    bf16_t* __restrict__ o) {
  __shared__ __align__(16) bf16_t Ks[64 * KPAD];
  __shared__ __align__(16) bf16_t Vs[64 * KPAD];
  __shared__ __align__(16) bf16_t Ps[4][16 * KPAD];
  int bid = blockIdx.x;
  int qi = 15 - (bid >> 6);
  int bh = bid & 63;
  int b = bh >> 4, h = bh & 15;
  const bf16_t* qb = q + ((size_t)bh << 16);
  const bf16_t* kb = kk + ((size_t)bh << 16);
  const bf16_t* vb = vt + ((size_t)bh << 16);
  int tid = threadIdx.x, lane = tid & 63, wave = tid >> 6;
  int lr = lane & 15, lg = lane >> 4;
  int qbase = qi * 64;

  bf16x8_t qf[2];
  {
    const bf16_t* qrow = qb + (size_t)(qbase + wave * 16 + lr) * D_ + lg * 8;
    qf[0] = *(const bf16x8_t*)(qrow);
    qf[1] = *(const bf16x8_t*)(qrow + 32);
  }

  float m_r[4], l_r[4];
  f32x4_t oc[4];
#pragma unroll
  for (int r = 0; r < 4; r++) { m_r[r] = -1e30f; l_r[r] = 0.f; }
#pragma unroll
  for (int j = 0; j < 4; j++) oc[j] = (f32x4_t){0.f, 0.f, 0.f, 0.f};

  int srow = tid >> 2, scol = (tid & 3) * 16;

  bf16x8_t k0, k1, v0, v1;
  {
    const bf16_t* kg = kb + (size_t)srow * D_ + scol;
    k0 = *(const bf16x8_t*)kg;
    k1 = *(const bf16x8_t*)(kg + 8);
    const bf16_t* vg = vb + (size_t)srow * T_ + scol;
    v0 = *(const bf16x8_t*)vg;
    v1 = *(const bf16x8_t*)(vg + 8);
  }

  for (int s = 0; s <= qi; s++) {
    __syncthreads();
    *(bf16x8_t*)(&Ks[srow * KPAD + scol]) = k0;
    *(bf16x8_t*)(&Ks[srow * KPAD + scol + 8]) = k1;
    *(bf16x8_t*)(&Vs[srow * KPAD + scol]) = v0;
    *(bf16x8_t*)(&Vs[srow * KPAD + scol + 8]) = v1;
    __syncthreads();

    if (s < qi) {
      int kv1 = (s + 1) * 64;
      const bf16_t* kg = kb + (size_t)(kv1 + srow) * D_ + scol;
      k0 = *(const bf16x8_t*)kg;
      k1 = *(const bf16x8_t*)(kg + 8);
      const bf16_t* vg = vb + (size_t)srow * T_ + kv1 + scol;
      v0 = *(const bf16x8_t*)vg;
      v1 = *(const bf16x8_t*)(vg + 8);
    }

    int kv0 = s * 64;
    f32x4_t sc[4];
    __builtin_amdgcn_s_setprio(1);
#pragma unroll
    for (int j = 0; j < 4; j++) {
      f32x4_t a = (f32x4_t){0.f, 0.f, 0.f, 0.f};
      bf16x8_t b0 = *(const bf16x8_t*)(&Ks[(j * 16 + lr) * KPAD + lg * 8]);
      bf16x8_t b1 = *(const bf16x8_t*)(&Ks[(j * 16 + lr) * KPAD + lg * 8 + 32]);
      a = __builtin_amdgcn_mfma_f32_16x16x32_bf16(qf[0], b0, a, 0, 0, 0);
      a = __builtin_amdgcn_mfma_f32_16x16x32_bf16(qf[1], b1, a, 0, 0, 0);
      sc[j] = a;
    }
    __builtin_amdgcn_s_setprio(0);
    if (s == qi) {
#pragma unroll
      for (int j = 0; j < 4; j++)
#pragma unroll
        for (int r = 0; r < 4; r++) {
          int kvp = kv0 + j * 16 + lr;
          int qp  = qbase + wave * 16 + lg * 4 + r;
          sc[j][r] = (kvp <= qp) ? sc[j][r] * 0.125f : -1e30f;
        }
    } else {
#pragma unroll
      for (int j = 0; j < 4; j++)
#pragma unroll
        for (int r = 0; r < 4; r++) sc[j][r] *= 0.125f;
    }

    float pm[4];
#pragma unroll
    for (int r = 0; r < 4; r++) {
      float v = fmaxf(fmaxf(sc[0][r], sc[1][r]), fmaxf(sc[2][r], sc[3][r]));
      v = fmaxf(v, __shfl_xor(v, 1, 64));
      v = fmaxf(v, __shfl_xor(v, 2, 64));
      v = fmaxf(v, __shfl_xor(v, 4, 64));
      v = fmaxf(v, __shfl_xor(v, 8, 64));
      pm[r] = v;
    }
    bool ok = (pm[0] - m_r[0] <= 8.f) && (pm[1] - m_r[1] <= 8.f) &&
              (pm[2] - m_r[2] <= 8.f) && (pm[3] - m_r[3] <= 8.f);
    if (!__all(ok)) {
#pragma unroll
      for (int r = 0; r < 4; r++) {
        float mn = fmaxf(m_r[r], pm[r]);
        float ex = __expf(m_r[r] - mn);
        m_r[r] = mn;
        l_r[r] *= ex;
#pragma unroll
        for (int j = 0; j < 4; j++) oc[j][r] *= ex;
      }
    }
#pragma unroll
    for (int j = 0; j < 4; j++)
#pragma unroll
      for (int r = 0; r < 4; r++) {
        float p = __expf(sc[j][r] - m_r[r]);
        l_r[r] += p;
        Ps[wave][(lg * 4 + r) * KPAD + j * 16 + lr] = f2b(p);
      }

    bf16x8_t pa0 = *(const bf16x8_t*)(&Ps[wave][lr * KPAD + lg * 8]);
    bf16x8_t pa1 = *(const bf16x8_t*)(&Ps[wave][lr * KPAD + lg * 8 + 32]);
    __builtin_amdgcn_s_setprio(1);
#pragma unroll
    for (int j = 0; j < 4; j++) {
      bf16x8_t vb0 = *(const bf16x8_t*)(&Vs[(j * 16 + lr) * KPAD + lg * 8]);
      bf16x8_t vb1 = *(const bf16x8_t*)(&Vs[(j * 16 + lr) * KPAD + lg * 8 + 32]);
      oc[j] = __builtin_amdgcn_mfma_f32_16x16x32_bf16(pa0, vb0, oc[j], 0, 0, 0);
      oc[j] = __builtin_amdgcn_mfma_f32_16x16x32_bf16(pa1, vb1, oc[j], 0, 0, 0);
    }
    __builtin_amdgcn_s_setprio(0);
  }

#pragma unroll
  for (int r = 0; r < 4; r++) {
    float v = l_r[r];
    v += __shfl_xor(v, 1, 64);
    v += __shfl_xor(v, 2, 64);
    v += __shfl_xor(v, 4, 64);
    v += __shfl_xor(v, 8, 64);
    l_r[r] = 1.f / v;
  }
  bf16_t* ob = o + ((size_t)(b * T_ + qbase + wave * 16)) * (H_ * D_) + h * D_;
#pragma unroll
  for (int j = 0; j < 4; j++)
#pragma unroll
    for (int r = 0; r < 4; r++) {
      int qrow = lg * 4 + r;
      ob[(size_t)qrow * (H_ * D_) + j * 16 + lr] = f2b(oc[j][r] * l_r[r]);
    }
}

// ---------------- host launch ----------------
extern "C" void kernel_launch(void* const* d_in, const int* in_sizes, int n_in,
                              void* d_out, int out_size, void* d_ws, size_t ws_size,
                              hipStream_t stream) {
  (void)in_sizes; (void)n_in; (void)out_size; (void)ws_size;
  const int*   tokens = (const int*)d_in[0];
  const float* tok_emb = (const float*)d_in[1];
  const float* pos_emb = (const float*)d_in[2];
  const float* Wq = (const float*)d_in[3];
  const float* Wk = (const float*)d_in[4];
  const float* Wv = (const float*)d_in[5];
  const float* Wo = (const float*)d_in[6];
  const float* bo = (const float*)d_in[7];
  const float* ln1_g = (const float*)d_in[8];
  const float* ln1_b = (const float*)d_in[9];
  const float* ln2_g = (const float*)d_in[10];
  const float* ln2_b = (const float*)d_in[11];
  const float* W1 = (const float*)d_in[12];
  const float* b1 = (const float*)d_in[13];
  const float* W2 = (const float*)d_in[14];
  const float* b2 = (const float*)d_in[15];
  const float* lnf_g = (const float*)d_in[16];
  const float* lnf_b = (const float*)d_in[17];
  const float* Wlm = (const float*)d_in[18];
  const float* blm = (const float*)d_in[19];

  char* w = (char*)d_ws;
  size_t off = 0;
  auto alloc = [&](size_t bytes) { void* p = (void*)(w + off); off += (bytes + 255) & ~(size_t)255; return p; };
  bf16_t* r    = (bf16_t*)alloc((size_t)MTOK * E_ * 2);
  bf16_t* t    = (bf16_t*)alloc((size_t)MTOK * E_ * 2);
  // q, kk, v contiguous (QKV scatter epilogue assumes section stride B*H*T*D)
  bf16_t* q    = (bf16_t*)alloc((size_t)B_ * H_ * T_ * D_ * 2);
  bf16_t* kk   = (bf16_t*)alloc((size_t)B_ * H_ * T_ * D_ * 2);
  bf16_t* v    = (bf16_t*)alloc((size_t)B_ * H_ * T_ * D_ * 2);  // [B,H,T,D]
  bf16_t* vt   = (bf16_t*)alloc((size_t)B_ * H_ * T_ * D_ * 2);  // [B,H,D,T]
  bf16_t* o    = (bf16_t*)alloc((size_t)MTOK * E_ * 2);
  bf16_t* h1   = (bf16_t*)alloc((size_t)MTOK * FF_ * 2);
  bf16_t* WqkvT = (bf16_t*)alloc((size_t)3 * E_ * H_ * D_ * 2);
  bf16_t* WoT  = (bf16_t*)alloc((size_t)E_ * H_ * D_ * 2);
  bf16_t* W1T  = (bf16_t*)alloc((size_t)E_ * FF_ * 2);
  bf16_t* W2T  = (bf16_t*)alloc((size_t)E_ * FF_ * 2);
  bf16_t* WlmT = (bf16_t*)alloc((size_t)E_ * V_ * 2);
  bf16_t* p2   = (bf16_t*)alloc((size_t)2 * MTOK * E_ * 2);

  embed_ln_kernel<<<MTOK, 256, 0, stream>>>(tokens, tok_emb, pos_emb, r, t, ln1_g, ln1_b);
  transpose_kernel<<<dim3(V_ / 32, E_ / 32), dim3(32, 8), 0, stream>>>(Wlm, WlmT, E_, V_);

  for (int l = 0; l < LAYERS; l++) {
    prep_weights_kernel<<<3072, 256, 0, stream>>>(
        Wq, Wk, Wv, Wo, W1, W2, WqkvT, WoT, W1T, W2T, l);

    gemm97_kernel<128, 128, MODE_QKV><<<dim3(24, 32, 1), 256, 0, stream>>>(
        t, 0, E_, WqkvT, 0, E_, q, 0, nullptr, nullptr, MTOK, 3 * H_ * D_, E_, 0);

    transpose_v_kernel<<<dim3(T_ / 64, B_ * H_), 256, 0, stream>>>(v, vt);

    flash_kernel<<<1024, 256, 0, stream>>>(q, kk, vt, o);

    gemm97_kernel<128, 128, MODE_BF16R><<<dim3(8, 32, 1), 256, 0, stream>>>(
        o, 0, H_ * D_, WoT, 0, H_ * D_, r, 0, bo + l * E_, t, MTOK, E_, H_ * D_, 0);

    ln_kernel<<<MTOK / 2, 256, 0, stream>>>(r, t, ln2_g + l * E_, ln2_b + l * E_);

    gemm3_kernel<MODE_BF16><<<dim3(32, 16, 1), 512, 0, stream>>>(
        t, E_, W1T, E_, h1, 0, b1 + l * FF_, MTOK, FF_, E_, 1);
    gemm3_kernel<MODE_BF16><<<dim3(8, 16, 2), 512, 0, stream>>>(
        h1, FF_, W2T, FF_, p2, (long long)MTOK * E_, nullptr, MTOK, E_, FF_ / 2, 0);
    const float* gn = (l + 1 < LAYERS) ? (ln1_g + (l + 1) * E_) : lnf_g;
    const float* bn = (l + 1 < LAYERS) ? (ln1_b + (l + 1) * E_) : lnf_b;
    reduce_ln_kernel<<<MTOK / 2, 256, 0, stream>>>(p2, t, b2 + l * E_, r, t, gn, bn);
  }

  gemm3_kernel<MODE_F32><<<dim3(16, 16, 1), 512, 0, stream>>>(
      t, E_, WlmT, E_, d_out, 0, blm, MTOK, V_, E_, 0);
}